// Round 7
// baseline (234.488 us; speedup 1.0000x reference)
//
#include <hip/hip_runtime.h>
#include <hip/hip_bf16.h>
#include <math.h>

// CrossAttention: B=2, S=4096, DIM=256, NH=8, DH=32.
// R6 = R2's proven flash (77us, verbatim) + wide-N GEMMs for the rest.
// LESSON (R3/R4): LDS strides MUST be multiples of 8 shorts (16B) or
// short8 ds_read_b128 degrades to split reads. All strides here = 40.
//   K0 prep_w   : transpose+bf16-split W -> [n][k] hi/lo (Wq prescaled)
//   K1 gemm_qkv : grid (128,3); block computes 64 m-rows x ALL 256 n-cols
//                 (X split once per m-tile; 48 MFMAs per wave per K-step)
//   K2 flash    : verbatim R2 (32 q/wave, LDS-staged K/V, P roundtrip)
//   K3 gemm_out : grid 128; same wide-N structure, xbuf @ Wp + bp

#define SCALE 0.17677669529663687f   // 32^-0.5
#define LOG2E 1.4426950408889634f

typedef __attribute__((ext_vector_type(8))) short short8;
typedef __attribute__((ext_vector_type(4))) float f32x4;

static __device__ __forceinline__ unsigned short f2bf(float x) {
    union { float f; unsigned int u; } v; v.f = x;
    unsigned int r = v.u + 0x7fff + ((v.u >> 16) & 1);   // RNE
    return (unsigned short)(r >> 16);
}
static __device__ __forceinline__ float bf2f(unsigned short h) {
    union { unsigned int u; float f; } v; v.u = ((unsigned int)h) << 16;
    return v.f;
}
static __device__ __forceinline__ float fexp2(float x) {
#if __has_builtin(__builtin_amdgcn_exp2f)
    return __builtin_amdgcn_exp2f(x);
#else
    float r; asm("v_exp_f32 %0, %1" : "=v"(r) : "v"(x)); return r;
#endif
}
// packed bf16 convert: low half = a, high half = b (gfx950 V_CVT_PK_BF16_F32)
static __device__ __forceinline__ unsigned int pk_bf16(float a, float b) {
    unsigned int r;
    asm("v_cvt_pk_bf16_f32 %0, %1, %2" : "=v"(r) : "v"(a), "v"(b));
    return r;
}

// ------------------------------------------------------- K0: W transpose+split
// grid 1024 x 256. Row layout: [0,256)=WqT(scaled) [256,512)=WkT [512,768)=WvT
// [768,1024)=WpT.  Output [n][k] bf16 hi/lo, k contiguous (256).
__global__ __launch_bounds__(256) void prep_w(
    const float* __restrict__ Wq, const float* __restrict__ Wkv,
    const float* __restrict__ Wp,
    unsigned short* __restrict__ whi, unsigned short* __restrict__ wlo)
{
    const int n = blockIdx.x & 255, mat = blockIdx.x >> 8, k = threadIdx.x;
    const float* src; int ldw, colx; float sc = 1.f;
    if (mat == 0)      { src = Wq;  ldw = 256; colx = n;       sc = SCALE * LOG2E; }
    else if (mat == 1) { src = Wkv; ldw = 512; colx = n;       }
    else if (mat == 2) { src = Wkv; ldw = 512; colx = n + 256; }
    else               { src = Wp;  ldw = 256; colx = n;       }
    float v = src[(long long)k * ldw + colx] * sc;
    unsigned short h = f2bf(v);
    unsigned short l = f2bf(v - bf2f(h));
    const int o = blockIdx.x * 256 + k;
    whi[o] = h; wlo[o] = l;
}

// --------------------------------------------------- K1: QKV wide-N MFMA GEMM
// grid (128, 3), block 256 (4 waves). by: 0=Q 1=K 2=V. m0=bx*64, n covers 256.
__global__ __launch_bounds__(256) void gemm_qkv(
    const float* __restrict__ query, const float* __restrict__ sim,
    const unsigned short* __restrict__ whi, const unsigned short* __restrict__ wlo,
    const float* __restrict__ bq, const float* __restrict__ bkv,
    unsigned short* __restrict__ qbuf, unsigned short* __restrict__ kbuf,
    unsigned short* __restrict__ vTb)
{
    __shared__ unsigned short XsH[64 * 40], XsL[64 * 40];
    __shared__ unsigned short WsH[256 * 40], WsL[256 * 40];

    const int t = threadIdx.x, wave = t >> 6, lane = t & 63;
    const int col = lane & 15, quad = lane >> 4;
    const int kind = blockIdx.y;          // 0=Q 1=K 2=V
    const int m0 = blockIdx.x * 64;
    const float* __restrict__ X = (kind == 0) ? query : sim;
    const int wrow0 = kind * 256;
    const int srow = t >> 2, spart = (t & 3) * 8;

    const f32x4 zero = {0.f, 0.f, 0.f, 0.f};
    f32x4 acc[16] = {zero, zero, zero, zero, zero, zero, zero, zero,
                     zero, zero, zero, zero, zero, zero, zero, zero};

    for (int kt = 0; kt < 8; ++kt) {
        const int k0 = kt * 32;
        // X staging: 64 rows x 32 k, split fp32 -> hi/lo (once per m-tile!)
        const float* xp = &X[(long long)(m0 + srow) * 256 + k0 + spart];
        float4 xa = *(const float4*)xp;
        float4 xb = *(const float4*)(xp + 4);
        float xv[8] = {xa.x, xa.y, xa.z, xa.w, xb.x, xb.y, xb.z, xb.w};
        union { unsigned short s[8]; uint4 u; } ph, pl;
#pragma unroll
        for (int j = 0; j < 8; ++j) {
            unsigned short h = f2bf(xv[j]);
            ph.s[j] = h;
            pl.s[j] = f2bf(xv[j] - bf2f(h));
        }
        // W staging: 256 rows x 32 k (pre-split bf16, aligned uint4 loads)
        uint4 wh[4], wl[4];
#pragma unroll
        for (int j = 0; j < 4; ++j) {
            wh[j] = *(const uint4*)&whi[(long long)(wrow0 + t) * 256 + k0 + j * 8];
            wl[j] = *(const uint4*)&wlo[(long long)(wrow0 + t) * 256 + k0 + j * 8];
        }
        __syncthreads();
        *(uint4*)&XsH[srow * 40 + spart] = ph.u;
        *(uint4*)&XsL[srow * 40 + spart] = pl.u;
#pragma unroll
        for (int j = 0; j < 4; ++j) {
            *(uint4*)&WsH[t * 40 + j * 8] = wh[j];
            *(uint4*)&WsL[t * 40 + j * 8] = wl[j];
        }
        __syncthreads();

        if (kind < 2) {   // C = X * W^T : A = X m-tile, B = W n-tiles
            short8 a_h = *(const short8*)(XsH + (wave * 16 + col) * 40 + quad * 8);
            short8 a_l = *(const short8*)(XsL + (wave * 16 + col) * 40 + quad * 8);
#pragma unroll
            for (int nt = 0; nt < 16; ++nt) {
                short8 b_h = *(const short8*)(WsH + (nt * 16 + col) * 40 + quad * 8);
                short8 b_l = *(const short8*)(WsL + (nt * 16 + col) * 40 + quad * 8);
                acc[nt] = __builtin_amdgcn_mfma_f32_16x16x32_bf16(a_h, b_h, acc[nt], 0, 0, 0);
                acc[nt] = __builtin_amdgcn_mfma_f32_16x16x32_bf16(a_l, b_h, acc[nt], 0, 0, 0);
                acc[nt] = __builtin_amdgcn_mfma_f32_16x16x32_bf16(a_h, b_l, acc[nt], 0, 0, 0);
            }
        } else {          // V transposed: A = W feature-tiles, B = X s-tiles
#pragma unroll
            for (int ft = 0; ft < 4; ++ft) {
                short8 a_h = *(const short8*)(WsH + (wave * 64 + ft * 16 + col) * 40 + quad * 8);
                short8 a_l = *(const short8*)(WsL + (wave * 64 + ft * 16 + col) * 40 + quad * 8);
#pragma unroll
                for (int nt = 0; nt < 4; ++nt) {
                    short8 b_h = *(const short8*)(XsH + (nt * 16 + col) * 40 + quad * 8);
                    short8 b_l = *(const short8*)(XsL + (nt * 16 + col) * 40 + quad * 8);
                    f32x4 a = acc[ft * 4 + nt];
                    a = __builtin_amdgcn_mfma_f32_16x16x32_bf16(a_h, b_h, a, 0, 0, 0);
                    a = __builtin_amdgcn_mfma_f32_16x16x32_bf16(a_l, b_h, a, 0, 0, 0);
                    a = __builtin_amdgcn_mfma_f32_16x16x32_bf16(a_h, b_l, a, 0, 0, 0);
                    acc[ft * 4 + nt] = a;
                }
            }
        }
    }

    if (kind == 0) {
#pragma unroll
        for (int nt = 0; nt < 16; ++nt) {
            int n = nt * 16 + col;
            int h = n >> 5, d = n & 31;
            float bias = bq[n] * (SCALE * LOG2E);
#pragma unroll
            for (int r = 0; r < 4; ++r) {
                int mg = m0 + wave * 16 + quad * 4 + r;
                int b = mg >> 12, sidx = mg & 4095;
                qbuf[((long long)(b * 8 + h) * 4096 + sidx) * 32 + d] = f2bf(acc[nt][r] + bias);
            }
        }
    } else if (kind == 1) {
#pragma unroll
        for (int nt = 0; nt < 16; ++nt) {
            int n = nt * 16 + col;
            int h = n >> 5, d = n & 31;
            float bias = bkv[n];
#pragma unroll
            for (int r = 0; r < 4; ++r) {
                int mg = m0 + wave * 16 + quad * 4 + r;
                int b = mg >> 12, sidx = mg & 4095;
                kbuf[((long long)(b * 8 + h) * 4096 + sidx) * 32 + d] = f2bf(acc[nt][r] + bias);
            }
        }
    } else {   // V: C[m'=feature][n'=s]
#pragma unroll
        for (int ft = 0; ft < 4; ++ft) {
#pragma unroll
            for (int nt = 0; nt < 4; ++nt) {
                int s = m0 + nt * 16 + col;
                int b = s >> 12, sidx = s & 4095;
#pragma unroll
                for (int r = 0; r < 4; ++r) {
                    int dcol = wave * 64 + ft * 16 + quad * 4 + r;
                    int h = dcol >> 5, dd = dcol & 31;
                    float bias = bkv[256 + dcol];
                    vTb[((long long)((b * 8 + h) * 32 + dd)) * 4096 + sidx] =
                        f2bf(acc[ft * 4 + nt][r] + bias);
                }
            }
        }
    }
}

// ------------------------------------------------------------ K2: flash MFMA
// VERBATIM R2 (measured 77us). grid 512 (16 bh x 32 q-blocks of 128),
// block 256. Wave owns 32 q (2 tiles). Strides 40/136 = 16B-aligned.
__global__ __launch_bounds__(256) void flash_mfma(
    const unsigned short* __restrict__ qbuf,
    const unsigned short* __restrict__ kbuf,
    const unsigned short* __restrict__ vT,
    float* __restrict__ xbuf)
{
    __shared__ unsigned short Ks[128 * 40];      // [key][dh] pad 32->40
    __shared__ unsigned short Vt[32 * 136];      // [dh][key] pad 128->136
    __shared__ unsigned short Pb[4][640];        // per-wave [q16][key] pad 32->40

    const int t = threadIdx.x;
    const int wave = t >> 6, lane = t & 63;
    const int col = lane & 15, quad = lane >> 4;
    const int bh = blockIdx.x >> 5;
    const int q0 = (blockIdx.x & 31) * 128 + wave * 32;
    const long long kvbase = (long long)bh * 4096 * 32;
    unsigned short* pbw = Pb[wave];

    const short8 qf0 = *(const short8*)(qbuf + kvbase + (long long)(q0 + col) * 32 + quad * 8);
    const short8 qf1 = *(const short8*)(qbuf + kvbase + (long long)(q0 + 16 + col) * 32 + quad * 8);

    const f32x4 zero = {0.f, 0.f, 0.f, 0.f};
    f32x4 o00 = zero, o01 = zero, o10 = zero, o11 = zero;
    float l0 = 0.f, l1 = 0.f;

    const int krow = t >> 2, kpart = (t & 3) * 8;
    const int vrow = t >> 4, vpart = (t & 15) * 8;

    for (int kt = 0; kt < 32; ++kt) {
        uint4 kg0 = *(const uint4*)(kbuf + kvbase + (long long)(kt * 128 + krow) * 32 + kpart);
        uint4 kg1 = *(const uint4*)(kbuf + kvbase + (long long)(kt * 128 + krow + 64) * 32 + kpart);
        uint4 vg0 = *(const uint4*)(vT + ((long long)(bh * 32 + vrow)) * 4096 + kt * 128 + vpart);
        uint4 vg1 = *(const uint4*)(vT + ((long long)(bh * 32 + vrow + 16)) * 4096 + kt * 128 + vpart);
        __syncthreads();
        *(uint4*)(Ks + krow * 40 + kpart) = kg0;
        *(uint4*)(Ks + (krow + 64) * 40 + kpart) = kg1;
        *(uint4*)(Vt + vrow * 136 + vpart) = vg0;
        *(uint4*)(Vt + (vrow + 16) * 136 + vpart) = vg1;
        __syncthreads();

#pragma unroll
        for (int sb = 0; sb < 4; ++sb) {
            const int kb = sb * 32;
            short8 a0 = *(const short8*)(Ks + (kb + col) * 40 + quad * 8);
            short8 a1 = *(const short8*)(Ks + (kb + 16 + col) * 40 + quad * 8);
            short8 v0 = *(const short8*)(Vt + col * 136 + kb + quad * 8);
            short8 v1 = *(const short8*)(Vt + (16 + col) * 136 + kb + quad * 8);
            // ---- q-tile 0
            {
                f32x4 c0 = __builtin_amdgcn_mfma_f32_16x16x32_bf16(a0, qf0, zero, 0, 0, 0);
                f32x4 c1 = __builtin_amdgcn_mfma_f32_16x16x32_bf16(a1, qf0, zero, 0, 0, 0);
                float p0 = fexp2(c0[0]), p1 = fexp2(c0[1]), p2 = fexp2(c0[2]), p3 = fexp2(c0[3]);
                float p4 = fexp2(c1[0]), p5 = fexp2(c1[1]), p6 = fexp2(c1[2]), p7 = fexp2(c1[3]);
                l0 += ((p0 + p1) + (p2 + p3)) + ((p4 + p5) + (p6 + p7));
                uint2 w0 = make_uint2(pk_bf16(p0, p1), pk_bf16(p2, p3));
                uint2 w1 = make_uint2(pk_bf16(p4, p5), pk_bf16(p6, p7));
                *(uint2*)(pbw + col * 40 + quad * 4) = w0;
                *(uint2*)(pbw + col * 40 + 16 + quad * 4) = w1;
                short8 pf = *(const short8*)(pbw + col * 40 + quad * 8);
                o00 = __builtin_amdgcn_mfma_f32_16x16x32_bf16(v0, pf, o00, 0, 0, 0);
                o01 = __builtin_amdgcn_mfma_f32_16x16x32_bf16(v1, pf, o01, 0, 0, 0);
            }
            // ---- q-tile 1 (reuse a0,a1,v0,v1)
            {
                f32x4 c0 = __builtin_amdgcn_mfma_f32_16x16x32_bf16(a0, qf1, zero, 0, 0, 0);
                f32x4 c1 = __builtin_amdgcn_mfma_f32_16x16x32_bf16(a1, qf1, zero, 0, 0, 0);
                float p0 = fexp2(c0[0]), p1 = fexp2(c0[1]), p2 = fexp2(c0[2]), p3 = fexp2(c0[3]);
                float p4 = fexp2(c1[0]), p5 = fexp2(c1[1]), p6 = fexp2(c1[2]), p7 = fexp2(c1[3]);
                l1 += ((p0 + p1) + (p2 + p3)) + ((p4 + p5) + (p6 + p7));
                uint2 w0 = make_uint2(pk_bf16(p0, p1), pk_bf16(p2, p3));
                uint2 w1 = make_uint2(pk_bf16(p4, p5), pk_bf16(p6, p7));
                *(uint2*)(pbw + col * 40 + quad * 4) = w0;
                *(uint2*)(pbw + col * 40 + 16 + quad * 4) = w1;
                short8 pf = *(const short8*)(pbw + col * 40 + quad * 8);
                o10 = __builtin_amdgcn_mfma_f32_16x16x32_bf16(v0, pf, o10, 0, 0, 0);
                o11 = __builtin_amdgcn_mfma_f32_16x16x32_bf16(v1, pf, o11, 0, 0, 0);
            }
        }
    }

    l0 += __shfl_xor(l0, 16, 64); l0 += __shfl_xor(l0, 32, 64);
    l1 += __shfl_xor(l1, 16, 64); l1 += __shfl_xor(l1, 32, 64);
    const float i0 = 1.f / l0, i1 = 1.f / l1;

    const int b = bh >> 3, hh = bh & 7;
    float* xp0 = xbuf + ((long long)(b * 4096 + q0 + col)) * 256 + hh * 32;
    *(float4*)(xp0 + quad * 4)      = make_float4(o00[0] * i0, o00[1] * i0, o00[2] * i0, o00[3] * i0);
    *(float4*)(xp0 + 16 + quad * 4) = make_float4(o01[0] * i0, o01[1] * i0, o01[2] * i0, o01[3] * i0);
    float* xp1 = xbuf + ((long long)(b * 4096 + q0 + 16 + col)) * 256 + hh * 32;
    *(float4*)(xp1 + quad * 4)      = make_float4(o10[0] * i1, o10[1] * i1, o10[2] * i1, o10[3] * i1);
    *(float4*)(xp1 + 16 + quad * 4) = make_float4(o11[0] * i1, o11[1] * i1, o11[2] * i1, o11[3] * i1);
}

// --------------------------------------------------- K3: out-proj wide-N MFMA
// grid 128, block 256. C = xbuf @ Wp + bp, all 256 n per block.
__global__ __launch_bounds__(256) void gemm_outp(
    const float* __restrict__ xbuf,
    const unsigned short* __restrict__ whi, const unsigned short* __restrict__ wlo,
    const float* __restrict__ bp, float* __restrict__ out)
{
    __shared__ unsigned short XsH[64 * 40], XsL[64 * 40];
    __shared__ unsigned short WsH[256 * 40], WsL[256 * 40];

    const int t = threadIdx.x, wave = t >> 6, lane = t & 63;
    const int col = lane & 15, quad = lane >> 4;
    const int m0 = blockIdx.x * 64;
    const int srow = t >> 2, spart = (t & 3) * 8;

    const f32x4 zero = {0.f, 0.f, 0.f, 0.f};
    f32x4 acc[16] = {zero, zero, zero, zero, zero, zero, zero, zero,
                     zero, zero, zero, zero, zero, zero, zero, zero};

    for (int kt = 0; kt < 8; ++kt) {
        const int k0 = kt * 32;
        const float* xp = &xbuf[(long long)(m0 + srow) * 256 + k0 + spart];
        float4 xa = *(const float4*)xp;
        float4 xb = *(const float4*)(xp + 4);
        float xv[8] = {xa.x, xa.y, xa.z, xa.w, xb.x, xb.y, xb.z, xb.w};
        union { unsigned short s[8]; uint4 u; } ph, pl;
#pragma unroll
        for (int j = 0; j < 8; ++j) {
            unsigned short h = f2bf(xv[j]);
            ph.s[j] = h;
            pl.s[j] = f2bf(xv[j] - bf2f(h));
        }
        uint4 wh[4], wl[4];
#pragma unroll
        for (int j = 0; j < 4; ++j) {
            wh[j] = *(const uint4*)&whi[(long long)(768 + t) * 256 + k0 + j * 8];
            wl[j] = *(const uint4*)&wlo[(long long)(768 + t) * 256 + k0 + j * 8];
        }
        __syncthreads();
        *(uint4*)&XsH[srow * 40 + spart] = ph.u;
        *(uint4*)&XsL[srow * 40 + spart] = pl.u;
#pragma unroll
        for (int j = 0; j < 4; ++j) {
            *(uint4*)&WsH[t * 40 + j * 8] = wh[j];
            *(uint4*)&WsL[t * 40 + j * 8] = wl[j];
        }
        __syncthreads();

        short8 a_h = *(const short8*)(XsH + (wave * 16 + col) * 40 + quad * 8);
        short8 a_l = *(const short8*)(XsL + (wave * 16 + col) * 40 + quad * 8);
#pragma unroll
        for (int nt = 0; nt < 16; ++nt) {
            short8 b_h = *(const short8*)(WsH + (nt * 16 + col) * 40 + quad * 8);
            short8 b_l = *(const short8*)(WsL + (nt * 16 + col) * 40 + quad * 8);
            acc[nt] = __builtin_amdgcn_mfma_f32_16x16x32_bf16(a_h, b_h, acc[nt], 0, 0, 0);
            acc[nt] = __builtin_amdgcn_mfma_f32_16x16x32_bf16(a_l, b_h, acc[nt], 0, 0, 0);
            acc[nt] = __builtin_amdgcn_mfma_f32_16x16x32_bf16(a_h, b_l, acc[nt], 0, 0, 0);
        }
    }

#pragma unroll
    for (int nt = 0; nt < 16; ++nt) {
        int n = nt * 16 + col;
        float bias = bp[n];
#pragma unroll
        for (int r = 0; r < 4; ++r) {
            int mg = m0 + wave * 16 + quad * 4 + r;
            out[(long long)mg * 256 + n] = acc[nt][r] + bias;
        }
    }
}

extern "C" void kernel_launch(void* const* d_in, const int* in_sizes, int n_in,
                              void* d_out, int out_size, void* d_ws, size_t ws_size,
                              hipStream_t stream) {
    const float* query = (const float*)d_in[0];
    const float* sim   = (const float*)d_in[1];
    const float* Wq    = (const float*)d_in[2];
    const float* bq    = (const float*)d_in[3];
    const float* Wkv   = (const float*)d_in[4];
    const float* bkv   = (const float*)d_in[5];
    const float* Wp    = (const float*)d_in[6];
    const float* bp    = (const float*)d_in[7];
    float* out = (float*)d_out;

    unsigned short* wsb = (unsigned short*)d_ws;
    unsigned short* qbuf = wsb;                        // 2,097,152 shorts
    unsigned short* kbuf = wsb + 2097152;
    unsigned short* vT   = wsb + 4194304;              // [bh][32][4096]
    float* xbuf = (float*)(wsb + 6291456);             // 2,097,152 floats
    unsigned short* whi  = wsb + 10485760;             // 1024*256
    unsigned short* wlo  = whi + 262144;

    prep_w   <<<dim3(1024),   256, 0, stream>>>(Wq, Wkv, Wp, whi, wlo);
    gemm_qkv <<<dim3(128, 3), 256, 0, stream>>>(query, sim, whi, wlo, bq, bkv,
                                                qbuf, kbuf, vT);
    flash_mfma<<<dim3(512),   256, 0, stream>>>(qbuf, kbuf, vT, xbuf);
    gemm_outp<<<dim3(128),    256, 0, stream>>>(xbuf, whi, wlo, bp, out);
}

// Round 8
// 172.592 us; speedup vs baseline: 1.3586x; 1.3586x over previous
//
#include <hip/hip_runtime.h>
#include <hip/hip_bf16.h>
#include <math.h>

// CrossAttention: B=2, S=4096, DIM=256, NH=8, DH=32.
// R7 = R2 GEMM structure (64x64 tiles, stride-40 LDS, grids 1536/512) with
// fp16 2-MFMA math (X split hi/lo fp16, W plain fp16 RNE) + pre-split X,
// + verbatim R2 flash (77us proven).
// LESSONS: LDS strides multiple of 8 elems (16B) or b128 degrades [R3/R4];
// grid >= 2 blocks/CU or GPU idles [R6]; flash is schedule-fragile [R3-R5].
//   K0 prep     : X -> fp16 hi/lo; W^T -> fp16 (coalesced LDS transpose)
//   K1 gemm_qkv : fp16 MFMA GEMM -> q(bf16 scaled), k(bf16), vT(bf16)
//   K2 flash    : verbatim R2
//   K3 gemm_outp: xbuf fp32 -> split fp16 on the fly, @ WpT fp16 + bp

#define SCALE 0.17677669529663687f   // 32^-0.5
#define LOG2E 1.4426950408889634f

typedef __attribute__((ext_vector_type(8))) short short8;
typedef __attribute__((ext_vector_type(8))) _Float16 half8;
typedef __attribute__((ext_vector_type(4))) float f32x4;

static __device__ __forceinline__ unsigned short f2bf(float x) {
    union { float f; unsigned int u; } v; v.f = x;
    unsigned int r = v.u + 0x7fff + ((v.u >> 16) & 1);   // RNE
    return (unsigned short)(r >> 16);
}
static __device__ __forceinline__ float bf2f(unsigned short h) {
    union { unsigned int u; float f; } v; v.u = ((unsigned int)h) << 16;
    return v.f;
}
static __device__ __forceinline__ float fexp2(float x) {
#if __has_builtin(__builtin_amdgcn_exp2f)
    return __builtin_amdgcn_exp2f(x);
#else
    float r; asm("v_exp_f32 %0, %1" : "=v"(r) : "v"(x)); return r;
#endif
}
static __device__ __forceinline__ unsigned int pk_bf16(float a, float b) {
    unsigned int r;
    asm("v_cvt_pk_bf16_f32 %0, %1, %2" : "=v"(r) : "v"(a), "v"(b));
    return r;
}
static __device__ __forceinline__ unsigned short f2h(float x) {
    _Float16 h = (_Float16)x;                  // v_cvt_f16_f32 (RNE)
    union { _Float16 h; unsigned short s; } u; u.h = h;
    return u.s;
}
static __device__ __forceinline__ float h2f(unsigned short s) {
    union { _Float16 h; unsigned short s; } u; u.s = s;
    return (float)u.h;
}

// -------------------------------------------------- K0: split X + W^T prep
// blocks [0,4096): X -> fp16 hi/lo (4 floats/thread).
// blocks [4096,4160): W 64x64 tile transpose via LDS -> fp16 [n][k].
__global__ __launch_bounds__(256) void prep(
    const float* __restrict__ query, const float* __restrict__ sim,
    const float* __restrict__ Wq, const float* __restrict__ Wkv,
    const float* __restrict__ Wp,
    unsigned short* __restrict__ xhi, unsigned short* __restrict__ xlo,
    unsigned short* __restrict__ wfp)
{
    __shared__ float T[64][68];
    const int blk = blockIdx.x, t = threadIdx.x;
    if (blk < 4096) {
        const int e = blk * 1024 + t * 4;
        const float* src = (e < 2097152) ? (query + e) : (sim + (e - 2097152));
        float4 v = *(const float4*)src;
        float xv[4] = {v.x, v.y, v.z, v.w};
        union { unsigned short s[4]; uint2 u; } ph, pl;
#pragma unroll
        for (int j = 0; j < 4; ++j) {
            unsigned short h = f2h(xv[j]);
            ph.s[j] = h;
            pl.s[j] = f2h(xv[j] - h2f(h));
        }
        *(uint2*)&xhi[e] = ph.u;
        *(uint2*)&xlo[e] = pl.u;
        return;
    }
    const int bb = blk - 4096;
    const int mat = bb >> 4, tile = bb & 15;
    const int kr0 = (tile >> 2) * 64;      // k rows in source
    const int nc0 = (tile & 3) * 64;       // n cols in source
    const float* src; int ldw, cb; float sc = 1.f;
    if (mat == 0)      { src = Wq;  ldw = 256; cb = 0;   sc = SCALE * LOG2E; }
    else if (mat == 1) { src = Wkv; ldw = 512; cb = 0;   }
    else if (mat == 2) { src = Wkv; ldw = 512; cb = 256; }
    else               { src = Wp;  ldw = 256; cb = 0;   }
    {
        const int rl = t >> 4, c4 = (t & 15) * 4;
#pragma unroll
        for (int rr = 0; rr < 4; ++rr) {
            float4 v = *(const float4*)&src[(long long)(kr0 + rr * 16 + rl) * ldw + cb + nc0 + c4];
            T[rr * 16 + rl][c4 + 0] = v.x; T[rr * 16 + rl][c4 + 1] = v.y;
            T[rr * 16 + rl][c4 + 2] = v.z; T[rr * 16 + rl][c4 + 3] = v.w;
        }
    }
    __syncthreads();
    {
        const int nl = t >> 2, kl0 = (t & 3) * 16;
        const long long orow = (long long)(mat * 256 + nc0 + nl) * 256 + kr0 + kl0;
        union { unsigned short s[16]; uint4 u[2]; } ph;
#pragma unroll
        for (int j = 0; j < 16; ++j)
            ph.s[j] = f2h(T[kl0 + j][nl] * sc);
        *(uint4*)&wfp[orow] = ph.u[0];
        *(uint4*)&wfp[orow + 8] = ph.u[1];
    }
}

// --------------------------------------------------- K1: QKV fp16 MFMA GEMM
// grid (128, 12), block 256 (4 waves). by>>2: 0=Q 1=K 2=V; n0=(by&3)*64.
__global__ __launch_bounds__(256) void gemm_qkv(
    const unsigned short* __restrict__ xhi, const unsigned short* __restrict__ xlo,
    const unsigned short* __restrict__ wfp,
    const float* __restrict__ bq, const float* __restrict__ bkv,
    unsigned short* __restrict__ qbuf, unsigned short* __restrict__ kbuf,
    unsigned short* __restrict__ vTb)
{
    __shared__ unsigned short XsH[64 * 40], XsL[64 * 40], Ws[64 * 40];

    const int t = threadIdx.x, wave = t >> 6, lane = t & 63;
    const int col = lane & 15, quad = lane >> 4;
    const int by = blockIdx.y;
    const int kind = by >> 2;             // 0=Q 1=K 2=V
    const int n0 = (by & 3) * 64;
    const int m0 = blockIdx.x * 64;
    const int xrow0 = ((kind == 0) ? 0 : 8192) + m0;
    const int wrow0 = kind * 256 + n0;
    const int srow = t >> 2, spart = (t & 3) * 8;

    const f32x4 zero = {0.f, 0.f, 0.f, 0.f};
    f32x4 acc[4] = {zero, zero, zero, zero};

    for (int kt = 0; kt < 8; ++kt) {
        const int k0 = kt * 32;
        uint4 xh = *(const uint4*)&xhi[(long long)(xrow0 + srow) * 256 + k0 + spart];
        uint4 xl = *(const uint4*)&xlo[(long long)(xrow0 + srow) * 256 + k0 + spart];
        uint4 wh = *(const uint4*)&wfp[(long long)(wrow0 + srow) * 256 + k0 + spart];
        __syncthreads();
        *(uint4*)&XsH[srow * 40 + spart] = xh;
        *(uint4*)&XsL[srow * 40 + spart] = xl;
        *(uint4*)&Ws[srow * 40 + spart] = wh;
        __syncthreads();

        if (kind < 2) {   // A = X m-tile (hi+lo), B = W n-tiles
            half8 a_h = *(const half8*)(XsH + (wave * 16 + col) * 40 + quad * 8);
            half8 a_l = *(const half8*)(XsL + (wave * 16 + col) * 40 + quad * 8);
#pragma unroll
            for (int nt = 0; nt < 4; ++nt) {
                half8 b = *(const half8*)(Ws + (nt * 16 + col) * 40 + quad * 8);
                acc[nt] = __builtin_amdgcn_mfma_f32_16x16x32_f16(a_h, b, acc[nt], 0, 0, 0);
                acc[nt] = __builtin_amdgcn_mfma_f32_16x16x32_f16(a_l, b, acc[nt], 0, 0, 0);
            }
        } else {          // V transposed: A = W feature-tile, B = X s-tiles (hi+lo)
            half8 a = *(const half8*)(Ws + (wave * 16 + col) * 40 + quad * 8);
#pragma unroll
            for (int nt = 0; nt < 4; ++nt) {
                half8 b_h = *(const half8*)(XsH + (nt * 16 + col) * 40 + quad * 8);
                half8 b_l = *(const half8*)(XsL + (nt * 16 + col) * 40 + quad * 8);
                acc[nt] = __builtin_amdgcn_mfma_f32_16x16x32_f16(a, b_h, acc[nt], 0, 0, 0);
                acc[nt] = __builtin_amdgcn_mfma_f32_16x16x32_f16(a, b_l, acc[nt], 0, 0, 0);
            }
        }
    }

    if (kind == 0) {
#pragma unroll
        for (int nt = 0; nt < 4; ++nt) {
            int n = n0 + nt * 16 + col;
            int h = n >> 5, d = n & 31;
            float bias = bq[n] * (SCALE * LOG2E);
#pragma unroll
            for (int r = 0; r < 4; ++r) {
                int mg = m0 + wave * 16 + quad * 4 + r;
                int b = mg >> 12, sidx = mg & 4095;
                qbuf[((long long)(b * 8 + h) * 4096 + sidx) * 32 + d] = f2bf(acc[nt][r] + bias);
            }
        }
    } else if (kind == 1) {
#pragma unroll
        for (int nt = 0; nt < 4; ++nt) {
            int n = n0 + nt * 16 + col;
            int h = n >> 5, d = n & 31;
            float bias = bkv[n];
#pragma unroll
            for (int r = 0; r < 4; ++r) {
                int mg = m0 + wave * 16 + quad * 4 + r;
                int b = mg >> 12, sidx = mg & 4095;
                kbuf[((long long)(b * 8 + h) * 4096 + sidx) * 32 + d] = f2bf(acc[nt][r] + bias);
            }
        }
    } else {   // V: C[m'=feature=wave*16+quad*4+r][n'=s=n-tiles over m0..m0+63]
#pragma unroll
        for (int nt = 0; nt < 4; ++nt) {
            int s = m0 + nt * 16 + col;
            int b = s >> 12, sidx = s & 4095;
#pragma unroll
            for (int r = 0; r < 4; ++r) {
                int dcol = n0 + wave * 16 + quad * 4 + r;
                int h = dcol >> 5, dd = dcol & 31;
                float bias = bkv[256 + dcol];
                vTb[((long long)((b * 8 + h) * 32 + dd)) * 4096 + sidx] = f2bf(acc[nt][r] + bias);
            }
        }
    }
}

// ------------------------------------------------------------ K2: flash MFMA
// VERBATIM R2 (measured 77us). grid 512, block 256. Strides 40/136 aligned.
__global__ __launch_bounds__(256) void flash_mfma(
    const unsigned short* __restrict__ qbuf,
    const unsigned short* __restrict__ kbuf,
    const unsigned short* __restrict__ vT,
    float* __restrict__ xbuf)
{
    __shared__ unsigned short Ks[128 * 40];      // [key][dh] pad 32->40
    __shared__ unsigned short Vt[32 * 136];      // [dh][key] pad 128->136
    __shared__ unsigned short Pb[4][640];        // per-wave [q16][key] pad 32->40

    const int t = threadIdx.x;
    const int wave = t >> 6, lane = t & 63;
    const int col = lane & 15, quad = lane >> 4;
    const int bh = blockIdx.x >> 5;
    const int q0 = (blockIdx.x & 31) * 128 + wave * 32;
    const long long kvbase = (long long)bh * 4096 * 32;
    unsigned short* pbw = Pb[wave];

    const short8 qf0 = *(const short8*)(qbuf + kvbase + (long long)(q0 + col) * 32 + quad * 8);
    const short8 qf1 = *(const short8*)(qbuf + kvbase + (long long)(q0 + 16 + col) * 32 + quad * 8);

    const f32x4 zero = {0.f, 0.f, 0.f, 0.f};
    f32x4 o00 = zero, o01 = zero, o10 = zero, o11 = zero;
    float l0 = 0.f, l1 = 0.f;

    const int krow = t >> 2, kpart = (t & 3) * 8;
    const int vrow = t >> 4, vpart = (t & 15) * 8;

    for (int kt = 0; kt < 32; ++kt) {
        uint4 kg0 = *(const uint4*)(kbuf + kvbase + (long long)(kt * 128 + krow) * 32 + kpart);
        uint4 kg1 = *(const uint4*)(kbuf + kvbase + (long long)(kt * 128 + krow + 64) * 32 + kpart);
        uint4 vg0 = *(const uint4*)(vT + ((long long)(bh * 32 + vrow)) * 4096 + kt * 128 + vpart);
        uint4 vg1 = *(const uint4*)(vT + ((long long)(bh * 32 + vrow + 16)) * 4096 + kt * 128 + vpart);
        __syncthreads();
        *(uint4*)(Ks + krow * 40 + kpart) = kg0;
        *(uint4*)(Ks + (krow + 64) * 40 + kpart) = kg1;
        *(uint4*)(Vt + vrow * 136 + vpart) = vg0;
        *(uint4*)(Vt + (vrow + 16) * 136 + vpart) = vg1;
        __syncthreads();

#pragma unroll
        for (int sb = 0; sb < 4; ++sb) {
            const int kb = sb * 32;
            short8 a0 = *(const short8*)(Ks + (kb + col) * 40 + quad * 8);
            short8 a1 = *(const short8*)(Ks + (kb + 16 + col) * 40 + quad * 8);
            short8 v0 = *(const short8*)(Vt + col * 136 + kb + quad * 8);
            short8 v1 = *(const short8*)(Vt + (16 + col) * 136 + kb + quad * 8);
            // ---- q-tile 0
            {
                f32x4 c0 = __builtin_amdgcn_mfma_f32_16x16x32_bf16(a0, qf0, zero, 0, 0, 0);
                f32x4 c1 = __builtin_amdgcn_mfma_f32_16x16x32_bf16(a1, qf0, zero, 0, 0, 0);
                float p0 = fexp2(c0[0]), p1 = fexp2(c0[1]), p2 = fexp2(c0[2]), p3 = fexp2(c0[3]);
                float p4 = fexp2(c1[0]), p5 = fexp2(c1[1]), p6 = fexp2(c1[2]), p7 = fexp2(c1[3]);
                l0 += ((p0 + p1) + (p2 + p3)) + ((p4 + p5) + (p6 + p7));
                uint2 w0 = make_uint2(pk_bf16(p0, p1), pk_bf16(p2, p3));
                uint2 w1 = make_uint2(pk_bf16(p4, p5), pk_bf16(p6, p7));
                *(uint2*)(pbw + col * 40 + quad * 4) = w0;
                *(uint2*)(pbw + col * 40 + 16 + quad * 4) = w1;
                short8 pf = *(const short8*)(pbw + col * 40 + quad * 8);
                o00 = __builtin_amdgcn_mfma_f32_16x16x32_bf16(v0, pf, o00, 0, 0, 0);
                o01 = __builtin_amdgcn_mfma_f32_16x16x32_bf16(v1, pf, o01, 0, 0, 0);
            }
            // ---- q-tile 1 (reuse a0,a1,v0,v1)
            {
                f32x4 c0 = __builtin_amdgcn_mfma_f32_16x16x32_bf16(a0, qf1, zero, 0, 0, 0);
                f32x4 c1 = __builtin_amdgcn_mfma_f32_16x16x32_bf16(a1, qf1, zero, 0, 0, 0);
                float p0 = fexp2(c0[0]), p1 = fexp2(c0[1]), p2 = fexp2(c0[2]), p3 = fexp2(c0[3]);
                float p4 = fexp2(c1[0]), p5 = fexp2(c1[1]), p6 = fexp2(c1[2]), p7 = fexp2(c1[3]);
                l1 += ((p0 + p1) + (p2 + p3)) + ((p4 + p5) + (p6 + p7));
                uint2 w0 = make_uint2(pk_bf16(p0, p1), pk_bf16(p2, p3));
                uint2 w1 = make_uint2(pk_bf16(p4, p5), pk_bf16(p6, p7));
                *(uint2*)(pbw + col * 40 + quad * 4) = w0;
                *(uint2*)(pbw + col * 40 + 16 + quad * 4) = w1;
                short8 pf = *(const short8*)(pbw + col * 40 + quad * 8);
                o10 = __builtin_amdgcn_mfma_f32_16x16x32_bf16(v0, pf, o10, 0, 0, 0);
                o11 = __builtin_amdgcn_mfma_f32_16x16x32_bf16(v1, pf, o11, 0, 0, 0);
            }
        }
    }

    l0 += __shfl_xor(l0, 16, 64); l0 += __shfl_xor(l0, 32, 64);
    l1 += __shfl_xor(l1, 16, 64); l1 += __shfl_xor(l1, 32, 64);
    const float i0 = 1.f / l0, i1 = 1.f / l1;

    const int b = bh >> 3, hh = bh & 7;
    float* xp0 = xbuf + ((long long)(b * 4096 + q0 + col)) * 256 + hh * 32;
    *(float4*)(xp0 + quad * 4)      = make_float4(o00[0] * i0, o00[1] * i0, o00[2] * i0, o00[3] * i0);
    *(float4*)(xp0 + 16 + quad * 4) = make_float4(o01[0] * i0, o01[1] * i0, o01[2] * i0, o01[3] * i0);
    float* xp1 = xbuf + ((long long)(b * 4096 + q0 + 16 + col)) * 256 + hh * 32;
    *(float4*)(xp1 + quad * 4)      = make_float4(o10[0] * i1, o10[1] * i1, o10[2] * i1, o10[3] * i1);
    *(float4*)(xp1 + 16 + quad * 4) = make_float4(o11[0] * i1, o11[1] * i1, o11[2] * i1, o11[3] * i1);
}

// --------------------------------------------------- K3: out-proj fp16 MFMA
// grid (128, 4), block 256. x split to fp16 hi/lo on the fly; Wp fp16.
__global__ __launch_bounds__(256) void gemm_outp(
    const float* __restrict__ xbuf, const unsigned short* __restrict__ wfp,
    const float* __restrict__ bp, float* __restrict__ out)
{
    __shared__ unsigned short XsH[64 * 40], XsL[64 * 40], Ws[64 * 40];

    const int t = threadIdx.x, wave = t >> 6, lane = t & 63;
    const int col = lane & 15, quad = lane >> 4;
    const int n0 = blockIdx.y * 64;
    const int m0 = blockIdx.x * 64;
    const int wrow0 = 768 + n0;
    const int srow = t >> 2, spart = (t & 3) * 8;

    const f32x4 zero = {0.f, 0.f, 0.f, 0.f};
    f32x4 acc[4] = {zero, zero, zero, zero};

    for (int kt = 0; kt < 8; ++kt) {
        const int k0 = kt * 32;
        const float* xp = &xbuf[(long long)(m0 + srow) * 256 + k0 + spart];
        float4 xa = *(const float4*)xp;
        float4 xb = *(const float4*)(xp + 4);
        float xv[8] = {xa.x, xa.y, xa.z, xa.w, xb.x, xb.y, xb.z, xb.w};
        union { unsigned short s[8]; uint4 u; } ph, pl;
#pragma unroll
        for (int j = 0; j < 8; ++j) {
            unsigned short h = f2h(xv[j]);
            ph.s[j] = h;
            pl.s[j] = f2h(xv[j] - h2f(h));
        }
        uint4 wh = *(const uint4*)&wfp[(long long)(wrow0 + srow) * 256 + k0 + spart];
        __syncthreads();
        *(uint4*)&XsH[srow * 40 + spart] = ph.u;
        *(uint4*)&XsL[srow * 40 + spart] = pl.u;
        *(uint4*)&Ws[srow * 40 + spart] = wh;
        __syncthreads();

        half8 a_h = *(const half8*)(XsH + (wave * 16 + col) * 40 + quad * 8);
        half8 a_l = *(const half8*)(XsL + (wave * 16 + col) * 40 + quad * 8);
#pragma unroll
        for (int nt = 0; nt < 4; ++nt) {
            half8 b = *(const half8*)(Ws + (nt * 16 + col) * 40 + quad * 8);
            acc[nt] = __builtin_amdgcn_mfma_f32_16x16x32_f16(a_h, b, acc[nt], 0, 0, 0);
            acc[nt] = __builtin_amdgcn_mfma_f32_16x16x32_f16(a_l, b, acc[nt], 0, 0, 0);
        }
    }

#pragma unroll
    for (int nt = 0; nt < 4; ++nt) {
        int n = n0 + nt * 16 + col;
        float bias = bp[n];
#pragma unroll
        for (int r = 0; r < 4; ++r) {
            int mg = m0 + wave * 16 + quad * 4 + r;
            out[(long long)mg * 256 + n] = acc[nt][r] + bias;
        }
    }
}

extern "C" void kernel_launch(void* const* d_in, const int* in_sizes, int n_in,
                              void* d_out, int out_size, void* d_ws, size_t ws_size,
                              hipStream_t stream) {
    const float* query = (const float*)d_in[0];
    const float* sim   = (const float*)d_in[1];
    const float* Wq    = (const float*)d_in[2];
    const float* bq    = (const float*)d_in[3];
    const float* Wkv   = (const float*)d_in[4];
    const float* bkv   = (const float*)d_in[5];
    const float* Wp    = (const float*)d_in[6];
    const float* bp    = (const float*)d_in[7];
    float* out = (float*)d_out;

    unsigned short* wsb = (unsigned short*)d_ws;
    unsigned short* qbuf = wsb;                        // 2,097,152 shorts
    unsigned short* kbuf = wsb + 2097152;
    unsigned short* vT   = wsb + 4194304;              // ends 6,291,456
    unsigned short* wfp  = wsb + 6291456;              // 262,144 fp16
    // xhi/xlo live until gemm_qkv done; xbuf (fp32, written by flash) aliases.
    unsigned short* xhi  = wsb + 6553600;              // 4,194,304
    unsigned short* xlo  = wsb + 10747904;             // ends 14,942,208
    float* xbuf = (float*)(wsb + 6553600);             // 2,097,152 floats

    prep      <<<dim3(4160),    256, 0, stream>>>(query, sim, Wq, Wkv, Wp,
                                                  xhi, xlo, wfp);
    gemm_qkv  <<<dim3(128, 12), 256, 0, stream>>>(xhi, xlo, wfp, bq, bkv,
                                                  qbuf, kbuf, vT);
    flash_mfma<<<dim3(512),     256, 0, stream>>>(qbuf, kbuf, vT, xbuf);
    gemm_outp <<<dim3(128, 4),  256, 0, stream>>>(xbuf, wfp, bp, out);
}

// Round 9
// 170.338 us; speedup vs baseline: 1.3766x; 1.0132x over previous
//
#include <hip/hip_runtime.h>
#include <hip/hip_bf16.h>
#include <math.h>

// CrossAttention: B=2, S=4096, DIM=256, NH=8, DH=32.
// R8 = R7 pipeline with flash upgraded to 64 q/wave + key-split x2,
// ALL LDS strides 16B-aligned (40/136 shorts) -- the R3/R4 collapse is
// fully attributed to misaligned strides (42/138), not the 64q shape.
//   K0 prep     : X -> fp16 hi/lo; W^T -> fp16 (coalesced LDS transpose)
//   K1 gemm_qkv : fp16 MFMA GEMM -> q(bf16 scaled), k(bf16), vT(bf16)
//   K2 flash    : 64 q/wave, ks2, fp32 unnormalized partials + l
//   K3 gemm_outp: combine partials * 1/l, split fp16, MFMA @ WpT + bp
// LESSONS: LDS strides multiple of 8 shorts (16B) [R3/R4/R6]; >=2 blocks/CU
// [R6]; flash K/V must stage through LDS, not direct-global [R5].

#define SCALE 0.17677669529663687f   // 32^-0.5
#define LOG2E 1.4426950408889634f

typedef __attribute__((ext_vector_type(8))) short short8;
typedef __attribute__((ext_vector_type(8))) _Float16 half8;
typedef __attribute__((ext_vector_type(4))) float f32x4;

static __device__ __forceinline__ unsigned short f2bf(float x) {
    union { float f; unsigned int u; } v; v.f = x;
    unsigned int r = v.u + 0x7fff + ((v.u >> 16) & 1);   // RNE
    return (unsigned short)(r >> 16);
}
static __device__ __forceinline__ float bf2f(unsigned short h) {
    union { unsigned int u; float f; } v; v.u = ((unsigned int)h) << 16;
    return v.f;
}
static __device__ __forceinline__ float fexp2(float x) {
#if __has_builtin(__builtin_amdgcn_exp2f)
    return __builtin_amdgcn_exp2f(x);
#else
    float r; asm("v_exp_f32 %0, %1" : "=v"(r) : "v"(x)); return r;
#endif
}
static __device__ __forceinline__ unsigned int pk_bf16(float a, float b) {
    unsigned int r;
    asm("v_cvt_pk_bf16_f32 %0, %1, %2" : "=v"(r) : "v"(a), "v"(b));
    return r;
}
static __device__ __forceinline__ unsigned short f2h(float x) {
    _Float16 h = (_Float16)x;
    union { _Float16 h; unsigned short s; } u; u.h = h;
    return u.s;
}
static __device__ __forceinline__ float h2f(unsigned short s) {
    union { _Float16 h; unsigned short s; } u; u.s = s;
    return (float)u.h;
}

// -------------------------------------------------- K0: split X + W^T prep
__global__ __launch_bounds__(256) void prep(
    const float* __restrict__ query, const float* __restrict__ sim,
    const float* __restrict__ Wq, const float* __restrict__ Wkv,
    const float* __restrict__ Wp,
    unsigned short* __restrict__ xhi, unsigned short* __restrict__ xlo,
    unsigned short* __restrict__ wfp)
{
    __shared__ float T[64][68];
    const int blk = blockIdx.x, t = threadIdx.x;
    if (blk < 4096) {
        const int e = blk * 1024 + t * 4;
        const float* src = (e < 2097152) ? (query + e) : (sim + (e - 2097152));
        float4 v = *(const float4*)src;
        float xv[4] = {v.x, v.y, v.z, v.w};
        union { unsigned short s[4]; uint2 u; } ph, pl;
#pragma unroll
        for (int j = 0; j < 4; ++j) {
            unsigned short h = f2h(xv[j]);
            ph.s[j] = h;
            pl.s[j] = f2h(xv[j] - h2f(h));
        }
        *(uint2*)&xhi[e] = ph.u;
        *(uint2*)&xlo[e] = pl.u;
        return;
    }
    const int bb = blk - 4096;
    const int mat = bb >> 4, tile = bb & 15;
    const int kr0 = (tile >> 2) * 64;
    const int nc0 = (tile & 3) * 64;
    const float* src; int ldw, cb; float sc = 1.f;
    if (mat == 0)      { src = Wq;  ldw = 256; cb = 0;   sc = SCALE * LOG2E; }
    else if (mat == 1) { src = Wkv; ldw = 512; cb = 0;   }
    else if (mat == 2) { src = Wkv; ldw = 512; cb = 256; }
    else               { src = Wp;  ldw = 256; cb = 0;   }
    {
        const int rl = t >> 4, c4 = (t & 15) * 4;
#pragma unroll
        for (int rr = 0; rr < 4; ++rr) {
            float4 v = *(const float4*)&src[(long long)(kr0 + rr * 16 + rl) * ldw + cb + nc0 + c4];
            T[rr * 16 + rl][c4 + 0] = v.x; T[rr * 16 + rl][c4 + 1] = v.y;
            T[rr * 16 + rl][c4 + 2] = v.z; T[rr * 16 + rl][c4 + 3] = v.w;
        }
    }
    __syncthreads();
    {
        const int nl = t >> 2, kl0 = (t & 3) * 16;
        const long long orow = (long long)(mat * 256 + nc0 + nl) * 256 + kr0 + kl0;
        union { unsigned short s[16]; uint4 u[2]; } ph;
#pragma unroll
        for (int j = 0; j < 16; ++j)
            ph.s[j] = f2h(T[kl0 + j][nl] * sc);
        *(uint4*)&wfp[orow] = ph.u[0];
        *(uint4*)&wfp[orow + 8] = ph.u[1];
    }
}

// --------------------------------------------------- K1: QKV fp16 MFMA GEMM
__global__ __launch_bounds__(256) void gemm_qkv(
    const unsigned short* __restrict__ xhi, const unsigned short* __restrict__ xlo,
    const unsigned short* __restrict__ wfp,
    const float* __restrict__ bq, const float* __restrict__ bkv,
    unsigned short* __restrict__ qbuf, unsigned short* __restrict__ kbuf,
    unsigned short* __restrict__ vTb)
{
    __shared__ unsigned short XsH[64 * 40], XsL[64 * 40], Ws[64 * 40];

    const int t = threadIdx.x, wave = t >> 6, lane = t & 63;
    const int col = lane & 15, quad = lane >> 4;
    const int by = blockIdx.y;
    const int kind = by >> 2;             // 0=Q 1=K 2=V
    const int n0 = (by & 3) * 64;
    const int m0 = blockIdx.x * 64;
    const int xrow0 = ((kind == 0) ? 0 : 8192) + m0;
    const int wrow0 = kind * 256 + n0;
    const int srow = t >> 2, spart = (t & 3) * 8;

    const f32x4 zero = {0.f, 0.f, 0.f, 0.f};
    f32x4 acc[4] = {zero, zero, zero, zero};

    for (int kt = 0; kt < 8; ++kt) {
        const int k0 = kt * 32;
        uint4 xh = *(const uint4*)&xhi[(long long)(xrow0 + srow) * 256 + k0 + spart];
        uint4 xl = *(const uint4*)&xlo[(long long)(xrow0 + srow) * 256 + k0 + spart];
        uint4 wh = *(const uint4*)&wfp[(long long)(wrow0 + srow) * 256 + k0 + spart];
        __syncthreads();
        *(uint4*)&XsH[srow * 40 + spart] = xh;
        *(uint4*)&XsL[srow * 40 + spart] = xl;
        *(uint4*)&Ws[srow * 40 + spart] = wh;
        __syncthreads();

        if (kind < 2) {
            half8 a_h = *(const half8*)(XsH + (wave * 16 + col) * 40 + quad * 8);
            half8 a_l = *(const half8*)(XsL + (wave * 16 + col) * 40 + quad * 8);
#pragma unroll
            for (int nt = 0; nt < 4; ++nt) {
                half8 b = *(const half8*)(Ws + (nt * 16 + col) * 40 + quad * 8);
                acc[nt] = __builtin_amdgcn_mfma_f32_16x16x32_f16(a_h, b, acc[nt], 0, 0, 0);
                acc[nt] = __builtin_amdgcn_mfma_f32_16x16x32_f16(a_l, b, acc[nt], 0, 0, 0);
            }
        } else {
            half8 a = *(const half8*)(Ws + (wave * 16 + col) * 40 + quad * 8);
#pragma unroll
            for (int nt = 0; nt < 4; ++nt) {
                half8 b_h = *(const half8*)(XsH + (nt * 16 + col) * 40 + quad * 8);
                half8 b_l = *(const half8*)(XsL + (nt * 16 + col) * 40 + quad * 8);
                acc[nt] = __builtin_amdgcn_mfma_f32_16x16x32_f16(a, b_h, acc[nt], 0, 0, 0);
                acc[nt] = __builtin_amdgcn_mfma_f32_16x16x32_f16(a, b_l, acc[nt], 0, 0, 0);
            }
        }
    }

    if (kind == 0) {
#pragma unroll
        for (int nt = 0; nt < 4; ++nt) {
            int n = n0 + nt * 16 + col;
            int h = n >> 5, d = n & 31;
            float bias = bq[n] * (SCALE * LOG2E);
#pragma unroll
            for (int r = 0; r < 4; ++r) {
                int mg = m0 + wave * 16 + quad * 4 + r;
                int b = mg >> 12, sidx = mg & 4095;
                qbuf[((long long)(b * 8 + h) * 4096 + sidx) * 32 + d] = f2bf(acc[nt][r] + bias);
            }
        }
    } else if (kind == 1) {
#pragma unroll
        for (int nt = 0; nt < 4; ++nt) {
            int n = n0 + nt * 16 + col;
            int h = n >> 5, d = n & 31;
            float bias = bkv[n];
#pragma unroll
            for (int r = 0; r < 4; ++r) {
                int mg = m0 + wave * 16 + quad * 4 + r;
                int b = mg >> 12, sidx = mg & 4095;
                kbuf[((long long)(b * 8 + h) * 4096 + sidx) * 32 + d] = f2bf(acc[nt][r] + bias);
            }
        }
    } else {
#pragma unroll
        for (int nt = 0; nt < 4; ++nt) {
            int s = m0 + nt * 16 + col;
            int b = s >> 12, sidx = s & 4095;
#pragma unroll
            for (int r = 0; r < 4; ++r) {
                int dcol = n0 + wave * 16 + quad * 4 + r;
                int h = dcol >> 5, dd = dcol & 31;
                float bias = bkv[256 + dcol];
                vTb[((long long)((b * 8 + h) * 32 + dd)) * 4096 + sidx] = f2bf(acc[nt][r] + bias);
            }
        }
    }
}

// ------------------------------------------------------------ K2: flash MFMA
// grid 512 = ks(2) x bh(16) x qb(16); block 256 (4 waves x 64 q).
// 64 q/wave: each K/V fragment feeds 4 q-tiles. ALL strides 16B-aligned.
// Writes unnormalized fp32 partials + l per key-split.
__global__ __launch_bounds__(256) void flash_mfma(
    const unsigned short* __restrict__ qbuf,
    const unsigned short* __restrict__ kbuf,
    const unsigned short* __restrict__ vT,
    float* __restrict__ xpart, float* __restrict__ lpart)
{
    __shared__ unsigned short Ks[128 * 40];      // [key][dh] pad 32->40 (16B ok)
    __shared__ unsigned short Vt[32 * 136];      // [dh][key] pad 128->136 (16B ok)
    __shared__ unsigned short Pb[16][640];       // [wave*4+tile][q16][key pad 40]

    const int t = threadIdx.x;
    const int wave = t >> 6, lane = t & 63;
    const int col = lane & 15, quad = lane >> 4;
    const int qb = blockIdx.x & 15;
    const int bh = (blockIdx.x >> 4) & 15;
    const int ks = blockIdx.x >> 8;
    const int q0 = qb * 256 + wave * 64;
    const long long kvbase = (long long)bh * 4096 * 32;

    short8 qf[4];
#pragma unroll
    for (int i = 0; i < 4; ++i)
        qf[i] = *(const short8*)(qbuf + kvbase + (long long)(q0 + i * 16 + col) * 32 + quad * 8);

    const f32x4 zero = {0.f, 0.f, 0.f, 0.f};
    f32x4 o[8] = {zero, zero, zero, zero, zero, zero, zero, zero};
    float l[4] = {0.f, 0.f, 0.f, 0.f};

    const int krow = t >> 2, kpart = (t & 3) * 8;
    const int vrow = t >> 4, vpart = (t & 15) * 8;

    for (int kt0 = 0; kt0 < 16; ++kt0) {
        const int kt = ks * 16 + kt0;
        uint4 kg0 = *(const uint4*)(kbuf + kvbase + (long long)(kt * 128 + krow) * 32 + kpart);
        uint4 kg1 = *(const uint4*)(kbuf + kvbase + (long long)(kt * 128 + krow + 64) * 32 + kpart);
        uint4 vg0 = *(const uint4*)(vT + ((long long)(bh * 32 + vrow)) * 4096 + kt * 128 + vpart);
        uint4 vg1 = *(const uint4*)(vT + ((long long)(bh * 32 + vrow + 16)) * 4096 + kt * 128 + vpart);
        __syncthreads();
        *(uint4*)(Ks + krow * 40 + kpart) = kg0;
        *(uint4*)(Ks + (krow + 64) * 40 + kpart) = kg1;
        *(uint4*)(Vt + vrow * 136 + vpart) = vg0;
        *(uint4*)(Vt + (vrow + 16) * 136 + vpart) = vg1;
        __syncthreads();

#pragma unroll
        for (int sb = 0; sb < 4; ++sb) {
            const int kb = sb * 32;
            short8 a0 = *(const short8*)(Ks + (kb + col) * 40 + quad * 8);
            short8 a1 = *(const short8*)(Ks + (kb + 16 + col) * 40 + quad * 8);
            short8 v0 = *(const short8*)(Vt + col * 136 + kb + quad * 8);
            short8 v1 = *(const short8*)(Vt + (16 + col) * 136 + kb + quad * 8);
#pragma unroll
            for (int i = 0; i < 4; ++i) {
                f32x4 c0 = __builtin_amdgcn_mfma_f32_16x16x32_bf16(a0, qf[i], zero, 0, 0, 0);
                f32x4 c1 = __builtin_amdgcn_mfma_f32_16x16x32_bf16(a1, qf[i], zero, 0, 0, 0);
                float p0 = fexp2(c0[0]), p1 = fexp2(c0[1]), p2 = fexp2(c0[2]), p3 = fexp2(c0[3]);
                float p4 = fexp2(c1[0]), p5 = fexp2(c1[1]), p6 = fexp2(c1[2]), p7 = fexp2(c1[3]);
                l[i] += ((p0 + p1) + (p2 + p3)) + ((p4 + p5) + (p6 + p7));
                uint2 w0 = make_uint2(pk_bf16(p0, p1), pk_bf16(p2, p3));
                uint2 w1 = make_uint2(pk_bf16(p4, p5), pk_bf16(p6, p7));
                unsigned short* pbw = Pb[wave * 4 + i];
                *(uint2*)(pbw + col * 40 + quad * 4) = w0;
                *(uint2*)(pbw + col * 40 + 16 + quad * 4) = w1;
                short8 pf = *(const short8*)(pbw + col * 40 + quad * 8);
                o[2 * i]     = __builtin_amdgcn_mfma_f32_16x16x32_bf16(v0, pf, o[2 * i], 0, 0, 0);
                o[2 * i + 1] = __builtin_amdgcn_mfma_f32_16x16x32_bf16(v1, pf, o[2 * i + 1], 0, 0, 0);
            }
        }
    }

#pragma unroll
    for (int i = 0; i < 4; ++i) {
        l[i] += __shfl_xor(l[i], 16, 64);
        l[i] += __shfl_xor(l[i], 32, 64);
    }

    const int b = bh >> 3, hh = bh & 7;
    float* xp = xpart + (long long)ks * 2097152;
#pragma unroll
    for (int i = 0; i < 4; ++i) {
        float* row = xp + ((long long)(b * 4096 + q0 + i * 16 + col)) * 256 + hh * 32;
        *(float4*)(row + quad * 4)      = make_float4(o[2*i][0], o[2*i][1], o[2*i][2], o[2*i][3]);
        *(float4*)(row + 16 + quad * 4) = make_float4(o[2*i+1][0], o[2*i+1][1], o[2*i+1][2], o[2*i+1][3]);
    }
    float lv = l[0];
    if (quad == 1) lv = l[1];
    else if (quad == 2) lv = l[2];
    else if (quad == 3) lv = l[3];
    lpart[ks * 65536 + bh * 4096 + q0 + quad * 16 + col] = lv;
}

// ----------------------------- K3: combine + normalize + out-proj fp16 MFMA
// grid (128, 4), block 256.
__global__ __launch_bounds__(256) void gemm_outp(
    const float* __restrict__ xpart, const float* __restrict__ lpart,
    const unsigned short* __restrict__ wfp,
    const float* __restrict__ bp, float* __restrict__ out)
{
    __shared__ unsigned short XsH[64 * 40], XsL[64 * 40], Ws[64 * 40];

    const int t = threadIdx.x, wave = t >> 6, lane = t & 63;
    const int col = lane & 15, quad = lane >> 4;
    const int n0 = blockIdx.y * 64;
    const int m0 = blockIdx.x * 64;
    const int wrow0 = 768 + n0;
    const int srow = t >> 2, spart = (t & 3) * 8;
    const int r = m0 + srow;
    const int bidx = r >> 12, s = r & 4095;
    const float* __restrict__ xa = xpart;
    const float* __restrict__ xb = xpart + 2097152;

    const f32x4 zero = {0.f, 0.f, 0.f, 0.f};
    f32x4 acc[4] = {zero, zero, zero, zero};

    for (int kt = 0; kt < 8; ++kt) {
        const int k0 = kt * 32;
        const int head = k0 >> 5;
        float la = lpart[(bidx * 8 + head) * 4096 + s];
        float lb = lpart[65536 + (bidx * 8 + head) * 4096 + s];
        float linv = 1.f / (la + lb);
        const float* pa = &xa[(long long)r * 256 + k0 + spart];
        const float* pb = &xb[(long long)r * 256 + k0 + spart];
        float4 a0 = *(const float4*)pa, a1 = *(const float4*)(pa + 4);
        float4 b0 = *(const float4*)pb, b1 = *(const float4*)(pb + 4);
        float xv[8] = {(a0.x + b0.x) * linv, (a0.y + b0.y) * linv,
                       (a0.z + b0.z) * linv, (a0.w + b0.w) * linv,
                       (a1.x + b1.x) * linv, (a1.y + b1.y) * linv,
                       (a1.z + b1.z) * linv, (a1.w + b1.w) * linv};
        union { unsigned short s4[8]; uint4 u; } ph, pl;
#pragma unroll
        for (int j = 0; j < 8; ++j) {
            unsigned short h = f2h(xv[j]);
            ph.s4[j] = h;
            pl.s4[j] = f2h(xv[j] - h2f(h));
        }
        uint4 wh = *(const uint4*)&wfp[(long long)(wrow0 + srow) * 256 + k0 + spart];
        __syncthreads();
        *(uint4*)&XsH[srow * 40 + spart] = ph.u;
        *(uint4*)&XsL[srow * 40 + spart] = pl.u;
        *(uint4*)&Ws[srow * 40 + spart] = wh;
        __syncthreads();

        half8 a_h = *(const half8*)(XsH + (wave * 16 + col) * 40 + quad * 8);
        half8 a_l = *(const half8*)(XsL + (wave * 16 + col) * 40 + quad * 8);
#pragma unroll
        for (int nt = 0; nt < 4; ++nt) {
            half8 b = *(const half8*)(Ws + (nt * 16 + col) * 40 + quad * 8);
            acc[nt] = __builtin_amdgcn_mfma_f32_16x16x32_f16(a_h, b, acc[nt], 0, 0, 0);
            acc[nt] = __builtin_amdgcn_mfma_f32_16x16x32_f16(a_l, b, acc[nt], 0, 0, 0);
        }
    }

#pragma unroll
    for (int nt = 0; nt < 4; ++nt) {
        int n = n0 + nt * 16 + col;
        float bias = bp[n];
#pragma unroll
        for (int rr = 0; rr < 4; ++rr) {
            int mg = m0 + wave * 16 + quad * 4 + rr;
            out[(long long)mg * 256 + n] = acc[nt][rr] + bias;
        }
    }
}

extern "C" void kernel_launch(void* const* d_in, const int* in_sizes, int n_in,
                              void* d_out, int out_size, void* d_ws, size_t ws_size,
                              hipStream_t stream) {
    const float* query = (const float*)d_in[0];
    const float* sim   = (const float*)d_in[1];
    const float* Wq    = (const float*)d_in[2];
    const float* bq    = (const float*)d_in[3];
    const float* Wkv   = (const float*)d_in[4];
    const float* bkv   = (const float*)d_in[5];
    const float* Wp    = (const float*)d_in[6];
    const float* bp    = (const float*)d_in[7];
    float* out = (float*)d_out;

    unsigned short* wsb = (unsigned short*)d_ws;
    unsigned short* qbuf = wsb;                        // 2,097,152 shorts
    unsigned short* kbuf = wsb + 2097152;
    unsigned short* vT   = wsb + 4194304;              // ends 6,291,456
    unsigned short* wfp  = wsb + 6291456;              // 262,144 fp16
    // xhi/xlo live until gemm_qkv done; xpart (written by flash) aliases them.
    unsigned short* xhi  = wsb + 6553600;              // 4,194,304 shorts
    unsigned short* xlo  = wsb + 10747904;             // ends 14,942,208
    float* xpart = (float*)(wsb + 6553600);            // 2 x 2,097,152 floats
    float* lpart = (float*)(wsb + 14942208);           // 2 x 65,536 floats

    prep      <<<dim3(4160),    256, 0, stream>>>(query, sim, Wq, Wkv, Wp,
                                                  xhi, xlo, wfp);
    gemm_qkv  <<<dim3(128, 12), 256, 0, stream>>>(xhi, xlo, wfp, bq, bkv,
                                                  qbuf, kbuf, vT);
    flash_mfma<<<dim3(512),     256, 0, stream>>>(qbuf, kbuf, vT, xpart, lpart);
    gemm_outp <<<dim3(128, 4),  256, 0, stream>>>(xpart, lpart, wfp, bp, out);
}

// Round 10
// 166.721 us; speedup vs baseline: 1.4065x; 1.0217x over previous
//
#include <hip/hip_runtime.h>
#include <hip/hip_bf16.h>
#include <math.h>

// CrossAttention: B=2, S=4096, DIM=256, NH=8, DH=32.
// R9 = R8 with ONE flash change: q-block 256->128 (32 q/wave, R2's proven
// inner body) while keeping key-split x2 -> grid 1024 = 4 blocks/CU
// (R8 was grid-limited to 2). This is "R4 with aligned strides" — a clean
// occupancy test with the alignment confound removed.
// LESSONS: LDS strides multiple of 8 shorts (16B) [R3/R4/R6]; >=2 blocks/CU
// [R6]; K/V via LDS not direct-global [R5]; 64q/wave reuse is neutral [R8].

#define SCALE 0.17677669529663687f   // 32^-0.5
#define LOG2E 1.4426950408889634f

typedef __attribute__((ext_vector_type(8))) short short8;
typedef __attribute__((ext_vector_type(8))) _Float16 half8;
typedef __attribute__((ext_vector_type(4))) float f32x4;

static __device__ __forceinline__ unsigned short f2bf(float x) {
    union { float f; unsigned int u; } v; v.f = x;
    unsigned int r = v.u + 0x7fff + ((v.u >> 16) & 1);   // RNE
    return (unsigned short)(r >> 16);
}
static __device__ __forceinline__ float bf2f(unsigned short h) {
    union { unsigned int u; float f; } v; v.u = ((unsigned int)h) << 16;
    return v.f;
}
static __device__ __forceinline__ float fexp2(float x) {
#if __has_builtin(__builtin_amdgcn_exp2f)
    return __builtin_amdgcn_exp2f(x);
#else
    float r; asm("v_exp_f32 %0, %1" : "=v"(r) : "v"(x)); return r;
#endif
}
static __device__ __forceinline__ unsigned int pk_bf16(float a, float b) {
    unsigned int r;
    asm("v_cvt_pk_bf16_f32 %0, %1, %2" : "=v"(r) : "v"(a), "v"(b));
    return r;
}
static __device__ __forceinline__ unsigned short f2h(float x) {
    _Float16 h = (_Float16)x;
    union { _Float16 h; unsigned short s; } u; u.h = h;
    return u.s;
}
static __device__ __forceinline__ float h2f(unsigned short s) {
    union { _Float16 h; unsigned short s; } u; u.s = s;
    return (float)u.h;
}

// -------------------------------------------------- K0: split X + W^T prep
__global__ __launch_bounds__(256) void prep(
    const float* __restrict__ query, const float* __restrict__ sim,
    const float* __restrict__ Wq, const float* __restrict__ Wkv,
    const float* __restrict__ Wp,
    unsigned short* __restrict__ xhi, unsigned short* __restrict__ xlo,
    unsigned short* __restrict__ wfp)
{
    __shared__ float T[64][68];
    const int blk = blockIdx.x, t = threadIdx.x;
    if (blk < 4096) {
        const int e = blk * 1024 + t * 4;
        const float* src = (e < 2097152) ? (query + e) : (sim + (e - 2097152));
        float4 v = *(const float4*)src;
        float xv[4] = {v.x, v.y, v.z, v.w};
        union { unsigned short s[4]; uint2 u; } ph, pl;
#pragma unroll
        for (int j = 0; j < 4; ++j) {
            unsigned short h = f2h(xv[j]);
            ph.s[j] = h;
            pl.s[j] = f2h(xv[j] - h2f(h));
        }
        *(uint2*)&xhi[e] = ph.u;
        *(uint2*)&xlo[e] = pl.u;
        return;
    }
    const int bb = blk - 4096;
    const int mat = bb >> 4, tile = bb & 15;
    const int kr0 = (tile >> 2) * 64;
    const int nc0 = (tile & 3) * 64;
    const float* src; int ldw, cb; float sc = 1.f;
    if (mat == 0)      { src = Wq;  ldw = 256; cb = 0;   sc = SCALE * LOG2E; }
    else if (mat == 1) { src = Wkv; ldw = 512; cb = 0;   }
    else if (mat == 2) { src = Wkv; ldw = 512; cb = 256; }
    else               { src = Wp;  ldw = 256; cb = 0;   }
    {
        const int rl = t >> 4, c4 = (t & 15) * 4;
#pragma unroll
        for (int rr = 0; rr < 4; ++rr) {
            float4 v = *(const float4*)&src[(long long)(kr0 + rr * 16 + rl) * ldw + cb + nc0 + c4];
            T[rr * 16 + rl][c4 + 0] = v.x; T[rr * 16 + rl][c4 + 1] = v.y;
            T[rr * 16 + rl][c4 + 2] = v.z; T[rr * 16 + rl][c4 + 3] = v.w;
        }
    }
    __syncthreads();
    {
        const int nl = t >> 2, kl0 = (t & 3) * 16;
        const long long orow = (long long)(mat * 256 + nc0 + nl) * 256 + kr0 + kl0;
        union { unsigned short s[16]; uint4 u[2]; } ph;
#pragma unroll
        for (int j = 0; j < 16; ++j)
            ph.s[j] = f2h(T[kl0 + j][nl] * sc);
        *(uint4*)&wfp[orow] = ph.u[0];
        *(uint4*)&wfp[orow + 8] = ph.u[1];
    }
}

// --------------------------------------------------- K1: QKV fp16 MFMA GEMM
__global__ __launch_bounds__(256) void gemm_qkv(
    const unsigned short* __restrict__ xhi, const unsigned short* __restrict__ xlo,
    const unsigned short* __restrict__ wfp,
    const float* __restrict__ bq, const float* __restrict__ bkv,
    unsigned short* __restrict__ qbuf, unsigned short* __restrict__ kbuf,
    unsigned short* __restrict__ vTb)
{
    __shared__ unsigned short XsH[64 * 40], XsL[64 * 40], Ws[64 * 40];

    const int t = threadIdx.x, wave = t >> 6, lane = t & 63;
    const int col = lane & 15, quad = lane >> 4;
    const int by = blockIdx.y;
    const int kind = by >> 2;             // 0=Q 1=K 2=V
    const int n0 = (by & 3) * 64;
    const int m0 = blockIdx.x * 64;
    const int xrow0 = ((kind == 0) ? 0 : 8192) + m0;
    const int wrow0 = kind * 256 + n0;
    const int srow = t >> 2, spart = (t & 3) * 8;

    const f32x4 zero = {0.f, 0.f, 0.f, 0.f};
    f32x4 acc[4] = {zero, zero, zero, zero};

    for (int kt = 0; kt < 8; ++kt) {
        const int k0 = kt * 32;
        uint4 xh = *(const uint4*)&xhi[(long long)(xrow0 + srow) * 256 + k0 + spart];
        uint4 xl = *(const uint4*)&xlo[(long long)(xrow0 + srow) * 256 + k0 + spart];
        uint4 wh = *(const uint4*)&wfp[(long long)(wrow0 + srow) * 256 + k0 + spart];
        __syncthreads();
        *(uint4*)&XsH[srow * 40 + spart] = xh;
        *(uint4*)&XsL[srow * 40 + spart] = xl;
        *(uint4*)&Ws[srow * 40 + spart] = wh;
        __syncthreads();

        if (kind < 2) {
            half8 a_h = *(const half8*)(XsH + (wave * 16 + col) * 40 + quad * 8);
            half8 a_l = *(const half8*)(XsL + (wave * 16 + col) * 40 + quad * 8);
#pragma unroll
            for (int nt = 0; nt < 4; ++nt) {
                half8 b = *(const half8*)(Ws + (nt * 16 + col) * 40 + quad * 8);
                acc[nt] = __builtin_amdgcn_mfma_f32_16x16x32_f16(a_h, b, acc[nt], 0, 0, 0);
                acc[nt] = __builtin_amdgcn_mfma_f32_16x16x32_f16(a_l, b, acc[nt], 0, 0, 0);
            }
        } else {
            half8 a = *(const half8*)(Ws + (wave * 16 + col) * 40 + quad * 8);
#pragma unroll
            for (int nt = 0; nt < 4; ++nt) {
                half8 b_h = *(const half8*)(XsH + (nt * 16 + col) * 40 + quad * 8);
                half8 b_l = *(const half8*)(XsL + (nt * 16 + col) * 40 + quad * 8);
                acc[nt] = __builtin_amdgcn_mfma_f32_16x16x32_f16(a, b_h, acc[nt], 0, 0, 0);
                acc[nt] = __builtin_amdgcn_mfma_f32_16x16x32_f16(a, b_l, acc[nt], 0, 0, 0);
            }
        }
    }

    if (kind == 0) {
#pragma unroll
        for (int nt = 0; nt < 4; ++nt) {
            int n = n0 + nt * 16 + col;
            int h = n >> 5, d = n & 31;
            float bias = bq[n] * (SCALE * LOG2E);
#pragma unroll
            for (int r = 0; r < 4; ++r) {
                int mg = m0 + wave * 16 + quad * 4 + r;
                int b = mg >> 12, sidx = mg & 4095;
                qbuf[((long long)(b * 8 + h) * 4096 + sidx) * 32 + d] = f2bf(acc[nt][r] + bias);
            }
        }
    } else if (kind == 1) {
#pragma unroll
        for (int nt = 0; nt < 4; ++nt) {
            int n = n0 + nt * 16 + col;
            int h = n >> 5, d = n & 31;
            float bias = bkv[n];
#pragma unroll
            for (int r = 0; r < 4; ++r) {
                int mg = m0 + wave * 16 + quad * 4 + r;
                int b = mg >> 12, sidx = mg & 4095;
                kbuf[((long long)(b * 8 + h) * 4096 + sidx) * 32 + d] = f2bf(acc[nt][r] + bias);
            }
        }
    } else {
#pragma unroll
        for (int nt = 0; nt < 4; ++nt) {
            int s = m0 + nt * 16 + col;
            int b = s >> 12, sidx = s & 4095;
#pragma unroll
            for (int r = 0; r < 4; ++r) {
                int dcol = n0 + wave * 16 + quad * 4 + r;
                int h = dcol >> 5, dd = dcol & 31;
                float bias = bkv[256 + dcol];
                vTb[((long long)((b * 8 + h) * 32 + dd)) * 4096 + sidx] = f2bf(acc[nt][r] + bias);
            }
        }
    }
}

// ------------------------------------------------------------ K2: flash MFMA
// grid 1024 = ks(2) x bh(16) x qb(32); block 256 (4 waves x 32 q).
// 4 blocks/CU (LDS 29,184 B). R2's proven inner body; partials + l out.
__global__ __launch_bounds__(256) void flash_mfma(
    const unsigned short* __restrict__ qbuf,
    const unsigned short* __restrict__ kbuf,
    const unsigned short* __restrict__ vT,
    float* __restrict__ xpart, float* __restrict__ lpart)
{
    __shared__ unsigned short Ks[128 * 40];      // [key][dh] pad 32->40 (16B ok)
    __shared__ unsigned short Vt[32 * 136];      // [dh][key] pad 128->136 (16B ok)
    __shared__ unsigned short Pb[8][640];        // [wave*2+tile][q16][key pad 40]

    const int t = threadIdx.x;
    const int wave = t >> 6, lane = t & 63;
    const int col = lane & 15, quad = lane >> 4;
    const int qb = blockIdx.x & 31;
    const int bh = (blockIdx.x >> 5) & 15;
    const int ks = blockIdx.x >> 9;
    const int q0 = qb * 128 + wave * 32;
    const long long kvbase = (long long)bh * 4096 * 32;
    unsigned short* pb0 = Pb[wave * 2];
    unsigned short* pb1 = Pb[wave * 2 + 1];

    const short8 qf0 = *(const short8*)(qbuf + kvbase + (long long)(q0 + col) * 32 + quad * 8);
    const short8 qf1 = *(const short8*)(qbuf + kvbase + (long long)(q0 + 16 + col) * 32 + quad * 8);

    const f32x4 zero = {0.f, 0.f, 0.f, 0.f};
    f32x4 o00 = zero, o01 = zero, o10 = zero, o11 = zero;
    float l0 = 0.f, l1 = 0.f;

    const int krow = t >> 2, kpart = (t & 3) * 8;
    const int vrow = t >> 4, vpart = (t & 15) * 8;

    for (int kt0 = 0; kt0 < 16; ++kt0) {
        const int kt = ks * 16 + kt0;
        uint4 kg0 = *(const uint4*)(kbuf + kvbase + (long long)(kt * 128 + krow) * 32 + kpart);
        uint4 kg1 = *(const uint4*)(kbuf + kvbase + (long long)(kt * 128 + krow + 64) * 32 + kpart);
        uint4 vg0 = *(const uint4*)(vT + ((long long)(bh * 32 + vrow)) * 4096 + kt * 128 + vpart);
        uint4 vg1 = *(const uint4*)(vT + ((long long)(bh * 32 + vrow + 16)) * 4096 + kt * 128 + vpart);
        __syncthreads();
        *(uint4*)(Ks + krow * 40 + kpart) = kg0;
        *(uint4*)(Ks + (krow + 64) * 40 + kpart) = kg1;
        *(uint4*)(Vt + vrow * 136 + vpart) = vg0;
        *(uint4*)(Vt + (vrow + 16) * 136 + vpart) = vg1;
        __syncthreads();

#pragma unroll
        for (int sb = 0; sb < 4; ++sb) {
            const int kb = sb * 32;
            short8 a0 = *(const short8*)(Ks + (kb + col) * 40 + quad * 8);
            short8 a1 = *(const short8*)(Ks + (kb + 16 + col) * 40 + quad * 8);
            short8 v0 = *(const short8*)(Vt + col * 136 + kb + quad * 8);
            short8 v1 = *(const short8*)(Vt + (16 + col) * 136 + kb + quad * 8);
            // ---- q-tile 0
            {
                f32x4 c0 = __builtin_amdgcn_mfma_f32_16x16x32_bf16(a0, qf0, zero, 0, 0, 0);
                f32x4 c1 = __builtin_amdgcn_mfma_f32_16x16x32_bf16(a1, qf0, zero, 0, 0, 0);
                float p0 = fexp2(c0[0]), p1 = fexp2(c0[1]), p2 = fexp2(c0[2]), p3 = fexp2(c0[3]);
                float p4 = fexp2(c1[0]), p5 = fexp2(c1[1]), p6 = fexp2(c1[2]), p7 = fexp2(c1[3]);
                l0 += ((p0 + p1) + (p2 + p3)) + ((p4 + p5) + (p6 + p7));
                uint2 w0 = make_uint2(pk_bf16(p0, p1), pk_bf16(p2, p3));
                uint2 w1 = make_uint2(pk_bf16(p4, p5), pk_bf16(p6, p7));
                *(uint2*)(pb0 + col * 40 + quad * 4) = w0;
                *(uint2*)(pb0 + col * 40 + 16 + quad * 4) = w1;
                short8 pf = *(const short8*)(pb0 + col * 40 + quad * 8);
                o00 = __builtin_amdgcn_mfma_f32_16x16x32_bf16(v0, pf, o00, 0, 0, 0);
                o01 = __builtin_amdgcn_mfma_f32_16x16x32_bf16(v1, pf, o01, 0, 0, 0);
            }
            // ---- q-tile 1 (reuse a0,a1,v0,v1)
            {
                f32x4 c0 = __builtin_amdgcn_mfma_f32_16x16x32_bf16(a0, qf1, zero, 0, 0, 0);
                f32x4 c1 = __builtin_amdgcn_mfma_f32_16x16x32_bf16(a1, qf1, zero, 0, 0, 0);
                float p0 = fexp2(c0[0]), p1 = fexp2(c0[1]), p2 = fexp2(c0[2]), p3 = fexp2(c0[3]);
                float p4 = fexp2(c1[0]), p5 = fexp2(c1[1]), p6 = fexp2(c1[2]), p7 = fexp2(c1[3]);
                l1 += ((p0 + p1) + (p2 + p3)) + ((p4 + p5) + (p6 + p7));
                uint2 w0 = make_uint2(pk_bf16(p0, p1), pk_bf16(p2, p3));
                uint2 w1 = make_uint2(pk_bf16(p4, p5), pk_bf16(p6, p7));
                *(uint2*)(pb1 + col * 40 + quad * 4) = w0;
                *(uint2*)(pb1 + col * 40 + 16 + quad * 4) = w1;
                short8 pf = *(const short8*)(pb1 + col * 40 + quad * 8);
                o10 = __builtin_amdgcn_mfma_f32_16x16x32_bf16(v0, pf, o10, 0, 0, 0);
                o11 = __builtin_amdgcn_mfma_f32_16x16x32_bf16(v1, pf, o11, 0, 0, 0);
            }
        }
    }

    l0 += __shfl_xor(l0, 16, 64); l0 += __shfl_xor(l0, 32, 64);
    l1 += __shfl_xor(l1, 16, 64); l1 += __shfl_xor(l1, 32, 64);

    const int b = bh >> 3, hh = bh & 7;
    float* xp = xpart + (long long)ks * 2097152;
    float* r0p = xp + ((long long)(b * 4096 + q0 + col)) * 256 + hh * 32;
    *(float4*)(r0p + quad * 4)      = make_float4(o00[0], o00[1], o00[2], o00[3]);
    *(float4*)(r0p + 16 + quad * 4) = make_float4(o01[0], o01[1], o01[2], o01[3]);
    float* r1p = xp + ((long long)(b * 4096 + q0 + 16 + col)) * 256 + hh * 32;
    *(float4*)(r1p + quad * 4)      = make_float4(o10[0], o10[1], o10[2], o10[3]);
    *(float4*)(r1p + 16 + quad * 4) = make_float4(o11[0], o11[1], o11[2], o11[3]);

    if (quad == 0)      lpart[ks * 65536 + bh * 4096 + q0 + col] = l0;
    else if (quad == 1) lpart[ks * 65536 + bh * 4096 + q0 + 16 + col] = l1;
}

// ----------------------------- K3: combine + normalize + out-proj fp16 MFMA
// grid (128, 4), block 256.
__global__ __launch_bounds__(256) void gemm_outp(
    const float* __restrict__ xpart, const float* __restrict__ lpart,
    const unsigned short* __restrict__ wfp,
    const float* __restrict__ bp, float* __restrict__ out)
{
    __shared__ unsigned short XsH[64 * 40], XsL[64 * 40], Ws[64 * 40];

    const int t = threadIdx.x, wave = t >> 6, lane = t & 63;
    const int col = lane & 15, quad = lane >> 4;
    const int n0 = blockIdx.y * 64;
    const int m0 = blockIdx.x * 64;
    const int wrow0 = 768 + n0;
    const int srow = t >> 2, spart = (t & 3) * 8;
    const int r = m0 + srow;
    const int bidx = r >> 12, s = r & 4095;
    const float* __restrict__ xa = xpart;
    const float* __restrict__ xb = xpart + 2097152;

    const f32x4 zero = {0.f, 0.f, 0.f, 0.f};
    f32x4 acc[4] = {zero, zero, zero, zero};

    for (int kt = 0; kt < 8; ++kt) {
        const int k0 = kt * 32;
        const int head = k0 >> 5;
        float la = lpart[(bidx * 8 + head) * 4096 + s];
        float lb = lpart[65536 + (bidx * 8 + head) * 4096 + s];
        float linv = 1.f / (la + lb);
        const float* pa = &xa[(long long)r * 256 + k0 + spart];
        const float* pb = &xb[(long long)r * 256 + k0 + spart];
        float4 a0 = *(const float4*)pa, a1 = *(const float4*)(pa + 4);
        float4 b0 = *(const float4*)pb, b1 = *(const float4*)(pb + 4);
        float xv[8] = {(a0.x + b0.x) * linv, (a0.y + b0.y) * linv,
                       (a0.z + b0.z) * linv, (a0.w + b0.w) * linv,
                       (a1.x + b1.x) * linv, (a1.y + b1.y) * linv,
                       (a1.z + b1.z) * linv, (a1.w + b1.w) * linv};
        union { unsigned short s4[8]; uint4 u; } ph, pl;
#pragma unroll
        for (int j = 0; j < 8; ++j) {
            unsigned short h = f2h(xv[j]);
            ph.s4[j] = h;
            pl.s4[j] = f2h(xv[j] - h2f(h));
        }
        uint4 wh = *(const uint4*)&wfp[(long long)(wrow0 + srow) * 256 + k0 + spart];
        __syncthreads();
        *(uint4*)&XsH[srow * 40 + spart] = ph.u;
        *(uint4*)&XsL[srow * 40 + spart] = pl.u;
        *(uint4*)&Ws[srow * 40 + spart] = wh;
        __syncthreads();

        half8 a_h = *(const half8*)(XsH + (wave * 16 + col) * 40 + quad * 8);
        half8 a_l = *(const half8*)(XsL + (wave * 16 + col) * 40 + quad * 8);
#pragma unroll
        for (int nt = 0; nt < 4; ++nt) {
            half8 b = *(const half8*)(Ws + (nt * 16 + col) * 40 + quad * 8);
            acc[nt] = __builtin_amdgcn_mfma_f32_16x16x32_f16(a_h, b, acc[nt], 0, 0, 0);
            acc[nt] = __builtin_amdgcn_mfma_f32_16x16x32_f16(a_l, b, acc[nt], 0, 0, 0);
        }
    }

#pragma unroll
    for (int nt = 0; nt < 4; ++nt) {
        int n = n0 + nt * 16 + col;
        float bias = bp[n];
#pragma unroll
        for (int rr = 0; rr < 4; ++rr) {
            int mg = m0 + wave * 16 + quad * 4 + rr;
            out[(long long)mg * 256 + n] = acc[nt][rr] + bias;
        }
    }
}

extern "C" void kernel_launch(void* const* d_in, const int* in_sizes, int n_in,
                              void* d_out, int out_size, void* d_ws, size_t ws_size,
                              hipStream_t stream) {
    const float* query = (const float*)d_in[0];
    const float* sim   = (const float*)d_in[1];
    const float* Wq    = (const float*)d_in[2];
    const float* bq    = (const float*)d_in[3];
    const float* Wkv   = (const float*)d_in[4];
    const float* bkv   = (const float*)d_in[5];
    const float* Wp    = (const float*)d_in[6];
    const float* bp    = (const float*)d_in[7];
    float* out = (float*)d_out;

    unsigned short* wsb = (unsigned short*)d_ws;
    unsigned short* qbuf = wsb;                        // 2,097,152 shorts
    unsigned short* kbuf = wsb + 2097152;
    unsigned short* vT   = wsb + 4194304;              // ends 6,291,456
    unsigned short* wfp  = wsb + 6291456;              // 262,144 fp16
    // xhi/xlo live until gemm_qkv done; xpart (written by flash) aliases them.
    unsigned short* xhi  = wsb + 6553600;              // 4,194,304 shorts
    unsigned short* xlo  = wsb + 10747904;             // ends 14,942,208
    float* xpart = (float*)(wsb + 6553600);            // 2 x 2,097,152 floats
    float* lpart = (float*)(wsb + 14942208);           // 2 x 65,536 floats

    prep      <<<dim3(4160),    256, 0, stream>>>(query, sim, Wq, Wkv, Wp,
                                                  xhi, xlo, wfp);
    gemm_qkv  <<<dim3(128, 12), 256, 0, stream>>>(xhi, xlo, wfp, bq, bkv,
                                                  qbuf, kbuf, vT);
    flash_mfma<<<dim3(1024),    256, 0, stream>>>(qbuf, kbuf, vT, xpart, lpart);
    gemm_outp <<<dim3(128, 4),  256, 0, stream>>>(xpart, lpart, wfp, bp, out);
}

// Round 11
// 158.909 us; speedup vs baseline: 1.4756x; 1.0492x over previous
//
#include <hip/hip_runtime.h>
#include <hip/hip_bf16.h>
#include <math.h>

// CrossAttention: B=2, S=4096, DIM=256, NH=8, DH=32.
// R10 = R9 with two attributed fixes:
//  (1) flash Vt stride 136->152 shorts: 68dw===4 (mod 32) caused 8-way bank
//      conflicts on Vt stage-writes AND fragment reads (28% of flash cycles,
//      SQ_LDS_BANK_CONFLICT=1.15e7). 152sh=76dw===12 mod 32 -> 3*col+quad
//      mod 8, Ks-quality ~2-way (free).
//  (2) gemm_qkv: single-fp16 X (bf16 storage of q/k/v dominates error at
//      4e-3 rel; fp16-X adds 1.5e-4 rel). Converts fp32 X in-kernel ->
//      4096-block X-prep pass deleted, LDS staging + MFMA count halved.
// LESSONS: LDS strides mult of 8 shorts AND stride/4 ≡ odd*4 mod 32 for
// b128 bank spread [R3..R10]; >=4 blocks/CU [R9]; K/V via LDS [R5].

#define SCALE 0.17677669529663687f   // 32^-0.5
#define LOG2E 1.4426950408889634f

typedef __attribute__((ext_vector_type(8))) short short8;
typedef __attribute__((ext_vector_type(8))) _Float16 half8;
typedef __attribute__((ext_vector_type(4))) float f32x4;

static __device__ __forceinline__ unsigned short f2bf(float x) {
    union { float f; unsigned int u; } v; v.f = x;
    unsigned int r = v.u + 0x7fff + ((v.u >> 16) & 1);   // RNE
    return (unsigned short)(r >> 16);
}
static __device__ __forceinline__ float bf2f(unsigned short h) {
    union { unsigned int u; float f; } v; v.u = ((unsigned int)h) << 16;
    return v.f;
}
static __device__ __forceinline__ float fexp2(float x) {
#if __has_builtin(__builtin_amdgcn_exp2f)
    return __builtin_amdgcn_exp2f(x);
#else
    float r; asm("v_exp_f32 %0, %1" : "=v"(r) : "v"(x)); return r;
#endif
}
static __device__ __forceinline__ unsigned int pk_bf16(float a, float b) {
    unsigned int r;
    asm("v_cvt_pk_bf16_f32 %0, %1, %2" : "=v"(r) : "v"(a), "v"(b));
    return r;
}
static __device__ __forceinline__ unsigned short f2h(float x) {
    _Float16 h = (_Float16)x;
    union { _Float16 h; unsigned short s; } u; u.h = h;
    return u.s;
}
static __device__ __forceinline__ float h2f(unsigned short s) {
    union { _Float16 h; unsigned short s; } u; u.s = s;
    return (float)u.h;
}

// -------------------------------------------------- K0: W^T -> fp16 prep
// grid 64: mat = blk>>4 (0=Wq scaled,1=Wk,2=Wv,3=Wp), 64x64 tile transpose.
__global__ __launch_bounds__(256) void prep(
    const float* __restrict__ Wq, const float* __restrict__ Wkv,
    const float* __restrict__ Wp, unsigned short* __restrict__ wfp)
{
    __shared__ float T[64][68];
    const int bb = blockIdx.x, t = threadIdx.x;
    const int mat = bb >> 4, tile = bb & 15;
    const int kr0 = (tile >> 2) * 64;
    const int nc0 = (tile & 3) * 64;
    const float* src; int ldw, cb; float sc = 1.f;
    if (mat == 0)      { src = Wq;  ldw = 256; cb = 0;   sc = SCALE * LOG2E; }
    else if (mat == 1) { src = Wkv; ldw = 512; cb = 0;   }
    else if (mat == 2) { src = Wkv; ldw = 512; cb = 256; }
    else               { src = Wp;  ldw = 256; cb = 0;   }
    {
        const int rl = t >> 4, c4 = (t & 15) * 4;
#pragma unroll
        for (int rr = 0; rr < 4; ++rr) {
            float4 v = *(const float4*)&src[(long long)(kr0 + rr * 16 + rl) * ldw + cb + nc0 + c4];
            T[rr * 16 + rl][c4 + 0] = v.x; T[rr * 16 + rl][c4 + 1] = v.y;
            T[rr * 16 + rl][c4 + 2] = v.z; T[rr * 16 + rl][c4 + 3] = v.w;
        }
    }
    __syncthreads();
    {
        const int nl = t >> 2, kl0 = (t & 3) * 16;
        const long long orow = (long long)(mat * 256 + nc0 + nl) * 256 + kr0 + kl0;
        union { unsigned short s[16]; uint4 u[2]; } ph;
#pragma unroll
        for (int j = 0; j < 16; ++j)
            ph.s[j] = f2h(T[kl0 + j][nl] * sc);
        *(uint4*)&wfp[orow] = ph.u[0];
        *(uint4*)&wfp[orow + 8] = ph.u[1];
    }
}

// --------------------------------------------- K1: QKV fp16 MFMA GEMM (1x)
// grid (128, 12), block 256. X converted fp32->fp16 during staging.
__global__ __launch_bounds__(256) void gemm_qkv(
    const float* __restrict__ query, const float* __restrict__ sim,
    const unsigned short* __restrict__ wfp,
    const float* __restrict__ bq, const float* __restrict__ bkv,
    unsigned short* __restrict__ qbuf, unsigned short* __restrict__ kbuf,
    unsigned short* __restrict__ vTb)
{
    __shared__ unsigned short Xs[64 * 40], Ws[64 * 40];

    const int t = threadIdx.x, wave = t >> 6, lane = t & 63;
    const int col = lane & 15, quad = lane >> 4;
    const int by = blockIdx.y;
    const int kind = by >> 2;             // 0=Q 1=K 2=V
    const int n0 = (by & 3) * 64;
    const int m0 = blockIdx.x * 64;
    const float* __restrict__ X = (kind == 0) ? query : sim;
    const int wrow0 = kind * 256 + n0;
    const int srow = t >> 2, spart = (t & 3) * 8;

    const f32x4 zero = {0.f, 0.f, 0.f, 0.f};
    f32x4 acc[4] = {zero, zero, zero, zero};

    for (int kt = 0; kt < 8; ++kt) {
        const int k0 = kt * 32;
        const float* xp = &X[(long long)(m0 + srow) * 256 + k0 + spart];
        float4 xa = *(const float4*)xp;
        float4 xb = *(const float4*)(xp + 4);
        float xv[8] = {xa.x, xa.y, xa.z, xa.w, xb.x, xb.y, xb.z, xb.w};
        union { unsigned short s[8]; uint4 u; } ph;
#pragma unroll
        for (int j = 0; j < 8; ++j) ph.s[j] = f2h(xv[j]);
        uint4 wh = *(const uint4*)&wfp[(long long)(wrow0 + srow) * 256 + k0 + spart];
        __syncthreads();
        *(uint4*)&Xs[srow * 40 + spart] = ph.u;
        *(uint4*)&Ws[srow * 40 + spart] = wh;
        __syncthreads();

        if (kind < 2) {
            half8 a = *(const half8*)(Xs + (wave * 16 + col) * 40 + quad * 8);
#pragma unroll
            for (int nt = 0; nt < 4; ++nt) {
                half8 b = *(const half8*)(Ws + (nt * 16 + col) * 40 + quad * 8);
                acc[nt] = __builtin_amdgcn_mfma_f32_16x16x32_f16(a, b, acc[nt], 0, 0, 0);
            }
        } else {
            half8 a = *(const half8*)(Ws + (wave * 16 + col) * 40 + quad * 8);
#pragma unroll
            for (int nt = 0; nt < 4; ++nt) {
                half8 b = *(const half8*)(Xs + (nt * 16 + col) * 40 + quad * 8);
                acc[nt] = __builtin_amdgcn_mfma_f32_16x16x32_f16(a, b, acc[nt], 0, 0, 0);
            }
        }
    }

    if (kind == 0) {
#pragma unroll
        for (int nt = 0; nt < 4; ++nt) {
            int n = n0 + nt * 16 + col;
            int h = n >> 5, d = n & 31;
            float bias = bq[n] * (SCALE * LOG2E);
#pragma unroll
            for (int r = 0; r < 4; ++r) {
                int mg = m0 + wave * 16 + quad * 4 + r;
                int b = mg >> 12, sidx = mg & 4095;
                qbuf[((long long)(b * 8 + h) * 4096 + sidx) * 32 + d] = f2bf(acc[nt][r] + bias);
            }
        }
    } else if (kind == 1) {
#pragma unroll
        for (int nt = 0; nt < 4; ++nt) {
            int n = n0 + nt * 16 + col;
            int h = n >> 5, d = n & 31;
            float bias = bkv[n];
#pragma unroll
            for (int r = 0; r < 4; ++r) {
                int mg = m0 + wave * 16 + quad * 4 + r;
                int b = mg >> 12, sidx = mg & 4095;
                kbuf[((long long)(b * 8 + h) * 4096 + sidx) * 32 + d] = f2bf(acc[nt][r] + bias);
            }
        }
    } else {
#pragma unroll
        for (int nt = 0; nt < 4; ++nt) {
            int s = m0 + nt * 16 + col;
            int b = s >> 12, sidx = s & 4095;
#pragma unroll
            for (int r = 0; r < 4; ++r) {
                int dcol = n0 + wave * 16 + quad * 4 + r;
                int h = dcol >> 5, dd = dcol & 31;
                float bias = bkv[256 + dcol];
                vTb[((long long)((b * 8 + h) * 32 + dd)) * 4096 + sidx] = f2bf(acc[nt][r] + bias);
            }
        }
    }
}

// ------------------------------------------------------------ K2: flash MFMA
// grid 1024 = ks(2) x bh(16) x qb(32); block 256 (4 waves x 32 q).
// Vt stride 152 shorts (76dw===12 mod 32): ~2-way banks like Ks.
__global__ __launch_bounds__(256) void flash_mfma(
    const unsigned short* __restrict__ qbuf,
    const unsigned short* __restrict__ kbuf,
    const unsigned short* __restrict__ vT,
    float* __restrict__ xpart, float* __restrict__ lpart)
{
    __shared__ unsigned short Ks[128 * 40];      // [key][dh] stride 40
    __shared__ unsigned short Vt[32 * 152];      // [dh][key] stride 152
    __shared__ unsigned short Pb[8][640];        // [wave*2+tile][q16][key pad 40]

    const int t = threadIdx.x;
    const int wave = t >> 6, lane = t & 63;
    const int col = lane & 15, quad = lane >> 4;
    const int qb = blockIdx.x & 31;
    const int bh = (blockIdx.x >> 5) & 15;
    const int ks = blockIdx.x >> 9;
    const int q0 = qb * 128 + wave * 32;
    const long long kvbase = (long long)bh * 4096 * 32;
    unsigned short* pb0 = Pb[wave * 2];
    unsigned short* pb1 = Pb[wave * 2 + 1];

    const short8 qf0 = *(const short8*)(qbuf + kvbase + (long long)(q0 + col) * 32 + quad * 8);
    const short8 qf1 = *(const short8*)(qbuf + kvbase + (long long)(q0 + 16 + col) * 32 + quad * 8);

    const f32x4 zero = {0.f, 0.f, 0.f, 0.f};
    f32x4 o00 = zero, o01 = zero, o10 = zero, o11 = zero;
    float l0 = 0.f, l1 = 0.f;

    const int krow = t >> 2, kpart = (t & 3) * 8;
    const int vrow = t >> 4, vpart = (t & 15) * 8;

    for (int kt0 = 0; kt0 < 16; ++kt0) {
        const int kt = ks * 16 + kt0;
        uint4 kg0 = *(const uint4*)(kbuf + kvbase + (long long)(kt * 128 + krow) * 32 + kpart);
        uint4 kg1 = *(const uint4*)(kbuf + kvbase + (long long)(kt * 128 + krow + 64) * 32 + kpart);
        uint4 vg0 = *(const uint4*)(vT + ((long long)(bh * 32 + vrow)) * 4096 + kt * 128 + vpart);
        uint4 vg1 = *(const uint4*)(vT + ((long long)(bh * 32 + vrow + 16)) * 4096 + kt * 128 + vpart);
        __syncthreads();
        *(uint4*)(Ks + krow * 40 + kpart) = kg0;
        *(uint4*)(Ks + (krow + 64) * 40 + kpart) = kg1;
        *(uint4*)(Vt + vrow * 152 + vpart) = vg0;
        *(uint4*)(Vt + (vrow + 16) * 152 + vpart) = vg1;
        __syncthreads();

#pragma unroll
        for (int sb = 0; sb < 4; ++sb) {
            const int kb = sb * 32;
            short8 a0 = *(const short8*)(Ks + (kb + col) * 40 + quad * 8);
            short8 a1 = *(const short8*)(Ks + (kb + 16 + col) * 40 + quad * 8);
            short8 v0 = *(const short8*)(Vt + col * 152 + kb + quad * 8);
            short8 v1 = *(const short8*)(Vt + (16 + col) * 152 + kb + quad * 8);
            // ---- q-tile 0
            {
                f32x4 c0 = __builtin_amdgcn_mfma_f32_16x16x32_bf16(a0, qf0, zero, 0, 0, 0);
                f32x4 c1 = __builtin_amdgcn_mfma_f32_16x16x32_bf16(a1, qf0, zero, 0, 0, 0);
                float p0 = fexp2(c0[0]), p1 = fexp2(c0[1]), p2 = fexp2(c0[2]), p3 = fexp2(c0[3]);
                float p4 = fexp2(c1[0]), p5 = fexp2(c1[1]), p6 = fexp2(c1[2]), p7 = fexp2(c1[3]);
                l0 += ((p0 + p1) + (p2 + p3)) + ((p4 + p5) + (p6 + p7));
                uint2 w0 = make_uint2(pk_bf16(p0, p1), pk_bf16(p2, p3));
                uint2 w1 = make_uint2(pk_bf16(p4, p5), pk_bf16(p6, p7));
                *(uint2*)(pb0 + col * 40 + quad * 4) = w0;
                *(uint2*)(pb0 + col * 40 + 16 + quad * 4) = w1;
                short8 pf = *(const short8*)(pb0 + col * 40 + quad * 8);
                o00 = __builtin_amdgcn_mfma_f32_16x16x32_bf16(v0, pf, o00, 0, 0, 0);
                o01 = __builtin_amdgcn_mfma_f32_16x16x32_bf16(v1, pf, o01, 0, 0, 0);
            }
            // ---- q-tile 1 (reuse a0,a1,v0,v1)
            {
                f32x4 c0 = __builtin_amdgcn_mfma_f32_16x16x32_bf16(a0, qf1, zero, 0, 0, 0);
                f32x4 c1 = __builtin_amdgcn_mfma_f32_16x16x32_bf16(a1, qf1, zero, 0, 0, 0);
                float p0 = fexp2(c0[0]), p1 = fexp2(c0[1]), p2 = fexp2(c0[2]), p3 = fexp2(c0[3]);
                float p4 = fexp2(c1[0]), p5 = fexp2(c1[1]), p6 = fexp2(c1[2]), p7 = fexp2(c1[3]);
                l1 += ((p0 + p1) + (p2 + p3)) + ((p4 + p5) + (p6 + p7));
                uint2 w0 = make_uint2(pk_bf16(p0, p1), pk_bf16(p2, p3));
                uint2 w1 = make_uint2(pk_bf16(p4, p5), pk_bf16(p6, p7));
                *(uint2*)(pb1 + col * 40 + quad * 4) = w0;
                *(uint2*)(pb1 + col * 40 + 16 + quad * 4) = w1;
                short8 pf = *(const short8*)(pb1 + col * 40 + quad * 8);
                o10 = __builtin_amdgcn_mfma_f32_16x16x32_bf16(v0, pf, o10, 0, 0, 0);
                o11 = __builtin_amdgcn_mfma_f32_16x16x32_bf16(v1, pf, o11, 0, 0, 0);
            }
        }
    }

    l0 += __shfl_xor(l0, 16, 64); l0 += __shfl_xor(l0, 32, 64);
    l1 += __shfl_xor(l1, 16, 64); l1 += __shfl_xor(l1, 32, 64);

    const int b = bh >> 3, hh = bh & 7;
    float* xp = xpart + (long long)ks * 2097152;
    float* r0p = xp + ((long long)(b * 4096 + q0 + col)) * 256 + hh * 32;
    *(float4*)(r0p + quad * 4)      = make_float4(o00[0], o00[1], o00[2], o00[3]);
    *(float4*)(r0p + 16 + quad * 4) = make_float4(o01[0], o01[1], o01[2], o01[3]);
    float* r1p = xp + ((long long)(b * 4096 + q0 + 16 + col)) * 256 + hh * 32;
    *(float4*)(r1p + quad * 4)      = make_float4(o10[0], o10[1], o10[2], o10[3]);
    *(float4*)(r1p + 16 + quad * 4) = make_float4(o11[0], o11[1], o11[2], o11[3]);

    if (quad == 0)      lpart[ks * 65536 + bh * 4096 + q0 + col] = l0;
    else if (quad == 1) lpart[ks * 65536 + bh * 4096 + q0 + 16 + col] = l1;
}

// ----------------------------- K3: combine + normalize + out-proj fp16 MFMA
// grid (128, 4), block 256. x split hi/lo fp16 (output accuracy path).
__global__ __launch_bounds__(256) void gemm_outp(
    const float* __restrict__ xpart, const float* __restrict__ lpart,
    const unsigned short* __restrict__ wfp,
    const float* __restrict__ bp, float* __restrict__ out)
{
    __shared__ unsigned short XsH[64 * 40], XsL[64 * 40], Ws[64 * 40];

    const int t = threadIdx.x, wave = t >> 6, lane = t & 63;
    const int col = lane & 15, quad = lane >> 4;
    const int n0 = blockIdx.y * 64;
    const int m0 = blockIdx.x * 64;
    const int wrow0 = 768 + n0;
    const int srow = t >> 2, spart = (t & 3) * 8;
    const int r = m0 + srow;
    const int bidx = r >> 12, s = r & 4095;
    const float* __restrict__ xa = xpart;
    const float* __restrict__ xb = xpart + 2097152;

    const f32x4 zero = {0.f, 0.f, 0.f, 0.f};
    f32x4 acc[4] = {zero, zero, zero, zero};

    for (int kt = 0; kt < 8; ++kt) {
        const int k0 = kt * 32;
        const int head = k0 >> 5;
        float la = lpart[(bidx * 8 + head) * 4096 + s];
        float lb = lpart[65536 + (bidx * 8 + head) * 4096 + s];
        float linv = 1.f / (la + lb);
        const float* pa = &xa[(long long)r * 256 + k0 + spart];
        const float* pb = &xb[(long long)r * 256 + k0 + spart];
        float4 a0 = *(const float4*)pa, a1 = *(const float4*)(pa + 4);
        float4 b0 = *(const float4*)pb, b1 = *(const float4*)(pb + 4);
        float xv[8] = {(a0.x + b0.x) * linv, (a0.y + b0.y) * linv,
                       (a0.z + b0.z) * linv, (a0.w + b0.w) * linv,
                       (a1.x + b1.x) * linv, (a1.y + b1.y) * linv,
                       (a1.z + b1.z) * linv, (a1.w + b1.w) * linv};
        union { unsigned short s4[8]; uint4 u; } ph, pl;
#pragma unroll
        for (int j = 0; j < 8; ++j) {
            unsigned short h = f2h(xv[j]);
            ph.s4[j] = h;
            pl.s4[j] = f2h(xv[j] - h2f(h));
        }
        uint4 wh = *(const uint4*)&wfp[(long long)(wrow0 + srow) * 256 + k0 + spart];
        __syncthreads();
        *(uint4*)&XsH[srow * 40 + spart] = ph.u;
        *(uint4*)&XsL[srow * 40 + spart] = pl.u;
        *(uint4*)&Ws[srow * 40 + spart] = wh;
        __syncthreads();

        half8 a_h = *(const half8*)(XsH + (wave * 16 + col) * 40 + quad * 8);
        half8 a_l = *(const half8*)(XsL + (wave * 16 + col) * 40 + quad * 8);
#pragma unroll
        for (int nt = 0; nt < 4; ++nt) {
            half8 b = *(const half8*)(Ws + (nt * 16 + col) * 40 + quad * 8);
            acc[nt] = __builtin_amdgcn_mfma_f32_16x16x32_f16(a_h, b, acc[nt], 0, 0, 0);
            acc[nt] = __builtin_amdgcn_mfma_f32_16x16x32_f16(a_l, b, acc[nt], 0, 0, 0);
        }
    }

#pragma unroll
    for (int nt = 0; nt < 4; ++nt) {
        int n = n0 + nt * 16 + col;
        float bias = bp[n];
#pragma unroll
        for (int rr = 0; rr < 4; ++rr) {
            int mg = m0 + wave * 16 + quad * 4 + rr;
            out[(long long)mg * 256 + n] = acc[nt][rr] + bias;
        }
    }
}

extern "C" void kernel_launch(void* const* d_in, const int* in_sizes, int n_in,
                              void* d_out, int out_size, void* d_ws, size_t ws_size,
                              hipStream_t stream) {
    const float* query = (const float*)d_in[0];
    const float* sim   = (const float*)d_in[1];
    const float* Wq    = (const float*)d_in[2];
    const float* bq    = (const float*)d_in[3];
    const float* Wkv   = (const float*)d_in[4];
    const float* bkv   = (const float*)d_in[5];
    const float* Wp    = (const float*)d_in[6];
    const float* bp    = (const float*)d_in[7];
    float* out = (float*)d_out;

    unsigned short* wsb = (unsigned short*)d_ws;
    unsigned short* qbuf = wsb;                        // 2,097,152 shorts
    unsigned short* kbuf = wsb + 2097152;
    unsigned short* vT   = wsb + 4194304;              // ends 6,291,456
    unsigned short* wfp  = wsb + 6291456;              // 262,144 fp16
    float* xpart = (float*)(wsb + 6553600);            // 2 x 2,097,152 floats
    float* lpart = (float*)(wsb + 14942208);           // 2 x 65,536 floats

    prep      <<<dim3(64),      256, 0, stream>>>(Wq, Wkv, Wp, wfp);
    gemm_qkv  <<<dim3(128, 12), 256, 0, stream>>>(query, sim, wfp, bq, bkv,
                                                  qbuf, kbuf, vT);
    flash_mfma<<<dim3(1024),    256, 0, stream>>>(qbuf, kbuf, vT, xpart, lpart);
    gemm_outp <<<dim3(128, 4),  256, 0, stream>>>(xpart, lpart, wfp, bp, out);
}